// Round 19
// baseline (224.238 us; speedup 1.0000x reference)
//
#include <hip/hip_runtime.h>
#include <hip/hip_bf16.h>

#define NN   30000
#define DIN  128
#define NHD  256      // H*D
#define HH   4
#define DD   64
#define MM   64
#define KK   6
#define EE   480000
#define ZOFF 1920000  // 30000*64
#define NCS   125
#define NP    250     // kvs partials (2 per chunk)
#define CHUNK 240
#define PITCH  30208   // padded bf16 elems per row of kbhT/vbhT
#define PITCH4 3776    // uint4 per row

typedef __attribute__((ext_vector_type(8))) short bf16x8;
typedef __attribute__((ext_vector_type(4))) float f32x4;
typedef __attribute__((ext_vector_type(2))) float f32x2;

__device__ __forceinline__ unsigned f2key(float f) {
    unsigned u = __float_as_uint(f);
    return (u & 0x80000000u) ? ~u : (u | 0x80000000u);
}
__device__ __forceinline__ float key2f(unsigned k) {
    return __uint_as_float((k & 0x80000000u) ? (k ^ 0x80000000u) : ~k);
}
__device__ __forceinline__ unsigned short f2bf(float f) {   // RNE
    unsigned u = __float_as_uint(f);
    unsigned r = ((u >> 16) & 1u) + 0x7fffu;
    return (unsigned short)((u + r) >> 16);
}
__device__ __forceinline__ float bf2f(unsigned short u) {
    return __uint_as_float((unsigned)u << 16);
}
// fp8 e4m3fn, POSITIVE values only, RNE, satfinite
__device__ __forceinline__ unsigned char ftofp8(float x) {
    unsigned u = __float_as_uint(x);
    int e32 = (int)(u >> 23) - 127;
    if (e32 <= -7) {                       // subnormal target (x < 2^-6)
        int m = (int)rintf(x * 512.f);     // RNE; m in [0,8]; m==8 == 2^-6 encoding
        return (unsigned char)m;
    }
    unsigned r = ((u >> 20) & 1u) + 0x7FFFFu;
    u += r;
    e32 = (int)(u >> 23) - 127;
    if (e32 > 8) return 0x7E;              // 448
    int m = (u >> 20) & 7;
    return (unsigned char)(((e32 + 7) << 3) | m);
}
__device__ __forceinline__ float fp8tof(unsigned char u) {
    int e = (u >> 3) & 15, m = u & 7;
    if (e == 0) return (float)m * 0.001953125f;              // m * 2^-9
    return __uint_as_float((unsigned)((e + 120) << 23) | ((unsigned)m << 20));
}
// decode 4 fp8 bytes of a uint -> 4 floats (HW converter when available)
__device__ __forceinline__ void fp8x4tof(unsigned w, float* o) {
#if __has_builtin(__builtin_amdgcn_cvt_pk_f32_fp8)
    f32x2 lo = __builtin_amdgcn_cvt_pk_f32_fp8((int)w, false);
    f32x2 hi = __builtin_amdgcn_cvt_pk_f32_fp8((int)w, true);
    o[0] = lo[0]; o[1] = lo[1]; o[2] = hi[0]; o[3] = hi[1];
#else
    o[0] = fp8tof((unsigned char)(w & 255));
    o[1] = fp8tof((unsigned char)((w >> 8) & 255));
    o[2] = fp8tof((unsigned char)((w >> 16) & 255));
    o[3] = fp8tof((unsigned char)((w >> 24) & 255));
#endif
}

// ---------------------------------------------------------------- init
__global__ void init_kernel(unsigned* gmax) {
    if (threadIdx.x < HH) gmax[threadIdx.x] = 0u;
}

// ---------------------------------------------------------------- K0a: z -> bf16
__global__ __launch_bounds__(256) void zcast_kernel(
    const float* __restrict__ z, unsigned short* __restrict__ zh) {
    int idx = blockIdx.x * 256 + threadIdx.x;   // 960,000 float4 exactly
    float4 v = ((const float4*)z)[idx];
    ushort4 u;
    u.x = f2bf(v.x); u.y = f2bf(v.y); u.z = f2bf(v.z); u.w = f2bf(v.w);
    ((ushort4*)zh)[idx] = u;
}

// ---------------------------------------------------------------- K0b: W [128][256] -> WT bf16 [256][128]
__global__ __launch_bounds__(256) void wtransp_kernel(
    const float* __restrict__ Wq, const float* __restrict__ Wk,
    const float* __restrict__ Wv, unsigned short* __restrict__ WT) {
    __shared__ unsigned short tl[64][72];
    const int t = threadIdx.x;
    const int kt = blockIdx.x & 1, ct = blockIdx.x >> 1;
    const int wi = blockIdx.y;
    const float* W = (wi == 0) ? Wq : (wi == 1) ? Wk : Wv;
    const float4* W4 = (const float4*)W;
    #pragma unroll
    for (int it = 0; it < 4; ++it) {
        int idx = t + it * 256;
        int r = idx >> 4, c4 = idx & 15;
        float4 v = W4[(kt * 64 + r) * 64 + ct * 16 + c4];
        tl[c4 * 4 + 0][r] = f2bf(v.x);
        tl[c4 * 4 + 1][r] = f2bf(v.y);
        tl[c4 * 4 + 2][r] = f2bf(v.z);
        tl[c4 * 4 + 3][r] = f2bf(v.w);
    }
    __syncthreads();
    uint4* d4 = (uint4*)WT;
    #pragma unroll
    for (int it = 0; it < 2; ++it) {
        int idx = t + it * 256;
        int m = idx >> 3, g = idx & 7;
        d4[((size_t)wi * 256 + ct * 64 + m) * 16 + kt * 8 + g] = *(uint4*)&tl[m][g * 8];
    }
}

// ---------------------------------------------------------------- K0c: proj*dn -> bf16
__global__ void projcast_kernel(const float* __restrict__ proj,
                                unsigned short* __restrict__ projh) {
    int i = blockIdx.x * 256 + threadIdx.x;   // 4096 exactly
    projh[i] = f2bf(proj[i] * 0.35355339059327373f);
}

// ---------------------------------------------------------------- K1: qkv via MFMA bf16, bf16 outputs
__global__ __launch_bounds__(256) void qkv_mfma_kernel(
    const unsigned short* __restrict__ zh, const unsigned short* __restrict__ WT,
    const float* __restrict__ bq, const float* __restrict__ bk, const float* __restrict__ bv,
    unsigned short* __restrict__ qh, unsigned short* __restrict__ kh,
    unsigned short* __restrict__ vh) {
    __shared__ __align__(16) unsigned short zt[128 * 128];
    __shared__ __align__(16) unsigned short wt[64 * 128];
    const int t = threadIdx.x;
    const int n0 = blockIdx.x * 128;
    const int wi = blockIdx.y;
    const float sc = (wi == 2) ? 1.0f : 2.0f;
    const float* bias = (wi == 0) ? bq : (wi == 1) ? bk : bv;
    unsigned short* outp = (wi == 0) ? qh : (wi == 1) ? kh : vh;
    const uint4* zg = (const uint4*)zh;
    #pragma unroll
    for (int it = 0; it < 8; ++it) {
        int idx = t + it * 256;
        int row = idx >> 4, g = idx & 15;
        int n = n0 + row;
        uint4 v = make_uint4(0u, 0u, 0u, 0u);
        if (n < NN) v = zg[(size_t)n * 16 + g];
        *(uint4*)&zt[row * 128 + ((g ^ (row & 7)) * 8)] = v;
    }
    const uint4* wg = (const uint4*)WT + (size_t)wi * 4096;
    const int w = t >> 6, lane = t & 63, lrow = lane & 15, lk = lane >> 4;
    for (int cc = 0; cc < 4; ++cc) {
        __syncthreads();
        #pragma unroll
        for (int it = 0; it < 4; ++it) {
            int idx = t + it * 256;
            int r = idx >> 4, g = idx & 15;
            *(uint4*)&wt[r * 128 + ((g ^ (r & 7)) * 8)] = wg[(cc * 64 + r) * 16 + g];
        }
        __syncthreads();
        f32x4 acc[4][2];
        #pragma unroll
        for (int mt = 0; mt < 4; ++mt) {
            acc[mt][0] = (f32x4){0.f, 0.f, 0.f, 0.f};
            acc[mt][1] = (f32x4){0.f, 0.f, 0.f, 0.f};
        }
        #pragma unroll
        for (int ks = 0; ks < 4; ++ks) {
            const int g0 = ks * 4 + lk;
            bf16x8 a[4], b[2];
            #pragma unroll
            for (int mt = 0; mt < 4; ++mt) {
                int r = mt * 16 + lrow;
                a[mt] = *(const bf16x8*)&wt[r * 128 + ((g0 ^ (r & 7)) * 8)];
            }
            #pragma unroll
            for (int nt = 0; nt < 2; ++nt) {
                int node = (w * 2 + nt) * 16 + lrow;
                b[nt] = *(const bf16x8*)&zt[node * 128 + ((g0 ^ (node & 7)) * 8)];
            }
            #pragma unroll
            for (int mt = 0; mt < 4; ++mt)
                #pragma unroll
                for (int nt = 0; nt < 2; ++nt)
                    acc[mt][nt] = __builtin_amdgcn_mfma_f32_16x16x32_bf16(
                        a[mt], b[nt], acc[mt][nt], 0, 0, 0);
        }
        #pragma unroll
        for (int mt = 0; mt < 4; ++mt) {
            int cbase = cc * 64 + mt * 16 + lk * 4;
            float4 bi = *(const float4*)&bias[cbase];
            #pragma unroll
            for (int nt = 0; nt < 2; ++nt) {
                int n = n0 + (w * 2 + nt) * 16 + lrow;
                if (n < NN) {
                    ushort4 u;
                    u.x = f2bf((acc[mt][nt][0] + bi.x) * sc);
                    u.y = f2bf((acc[mt][nt][1] + bi.y) * sc);
                    u.z = f2bf((acc[mt][nt][2] + bi.z) * sc);
                    u.w = f2bf((acc[mt][nt][3] + bi.w) * sc);
                    *(ushort4*)&outp[(size_t)n * NHD + cbase] = u;
                }
            }
        }
    }
}

// ---------------------------------------------------------------- K2: random features via MFMA
__global__ __launch_bounds__(256) void feat_mfma_kernel(
    unsigned short* __restrict__ qbh, const unsigned short* __restrict__ kh,
    float* __restrict__ kb, const unsigned short* __restrict__ projh,
    unsigned* __restrict__ gmax) {
    __shared__ __align__(16) unsigned short at[64 * 64];
    __shared__ __align__(16) unsigned short pb[64 * 64];
    __shared__ __align__(16) float ddt[64 * 68];
    __shared__ float diag_sh[64];
    __shared__ float wmax_sh[4];
    const int t = threadIdx.x;
    const int h = blockIdx.y;
    const int n0 = blockIdx.x * 64;
    const int tx = t & 15, ty = t >> 4;
    const uint4* pg = (const uint4*)projh;
    #pragma unroll
    for (int q = 0; q < 2; ++q) {
        int idx = t + q * 256;
        int m = idx >> 3, g = idx & 7;
        *(uint4*)&pb[m * 64 + ((g ^ (m & 7)) * 8)] = pg[idx];
    }
    const int w = t >> 6, lane = t & 63, lrow = lane & 15, lk = lane >> 4;
    const int arow = w * 16 + lrow;
    #pragma unroll
    for (int pass = 0; pass < 2; ++pass) {
        const uint4* src = (const uint4*)(pass ? kh : qbh);
        __syncthreads();
        #pragma unroll
        for (int q = 0; q < 2; ++q) {
            int idx = t + q * 256;
            int n = idx >> 3, g = idx & 7;
            uint4 v = make_uint4(0u, 0u, 0u, 0u);
            if (n0 + n < NN) v = src[(size_t)(n0 + n) * 32 + h * 8 + g];
            *(uint4*)&at[n * 64 + ((g ^ (n & 7)) * 8)] = v;
            const unsigned short* e8 = (const unsigned short*)&v;
            float ss = 0.f;
            #pragma unroll
            for (int j2 = 0; j2 < 8; ++j2) { float f = bf2f(e8[j2]); ss += f * f; }
            ss += __shfl_xor(ss, 1, 64);
            ss += __shfl_xor(ss, 2, 64);
            ss += __shfl_xor(ss, 4, 64);
            if (g == 0) diag_sh[n] = 0.0625f * ss;   // 0.5 * dn^2 * sum
        }
        __syncthreads();
        bf16x8 a0 = *(const bf16x8*)&at[arow * 64 + ((lk ^ (arow & 7)) * 8)];
        bf16x8 a1 = *(const bf16x8*)&at[arow * 64 + (((lk + 4) ^ (arow & 7)) * 8)];
        #pragma unroll
        for (int ct = 0; ct < 4; ++ct) {
            int brow = ct * 16 + lrow;
            bf16x8 b0 = *(const bf16x8*)&pb[brow * 64 + ((lk ^ (brow & 7)) * 8)];
            bf16x8 b1 = *(const bf16x8*)&pb[brow * 64 + (((lk + 4) ^ (brow & 7)) * 8)];
            f32x4 acc = {0.f, 0.f, 0.f, 0.f};
            acc = __builtin_amdgcn_mfma_f32_16x16x32_bf16(a0, b0, acc, 0, 0, 0);
            acc = __builtin_amdgcn_mfma_f32_16x16x32_bf16(a1, b1, acc, 0, 0, 0);
            #pragma unroll
            for (int r = 0; r < 4; ++r)
                ddt[(w * 16 + lk * 4 + r) * 68 + ct * 16 + lrow] = acc[r];
        }
        __syncthreads();
        if (pass == 0) {
            #pragma unroll
            for (int i = 0; i < 4; ++i) {
                int n = n0 + ty * 4 + i;
                float a_[4];
                #pragma unroll
                for (int j = 0; j < 4; ++j) a_[j] = ddt[(ty * 4 + i) * 68 + tx * 4 + j];
                float mx = fmaxf(fmaxf(a_[0], a_[1]), fmaxf(a_[2], a_[3]));
                mx = fmaxf(mx, __shfl_xor(mx, 1, 64));
                mx = fmaxf(mx, __shfl_xor(mx, 2, 64));
                mx = fmaxf(mx, __shfl_xor(mx, 4, 64));
                mx = fmaxf(mx, __shfl_xor(mx, 8, 64));
                if (n < NN) {
                    float dg = diag_sh[ty * 4 + i] + mx;
                    ushort4 u;
                    u.x = f2bf(0.125f * (__expf(a_[0] - dg) + 1e-6f));
                    u.y = f2bf(0.125f * (__expf(a_[1] - dg) + 1e-6f));
                    u.z = f2bf(0.125f * (__expf(a_[2] - dg) + 1e-6f));
                    u.w = f2bf(0.125f * (__expf(a_[3] - dg) + 1e-6f));
                    *(ushort4*)&qbh[(size_t)n * NHD + h * DD + tx * 4] = u;
                }
            }
        } else {
            float km = -3.4e38f;
            #pragma unroll
            for (int i = 0; i < 4; ++i) {
                int n = n0 + ty * 4 + i;
                if (n < NN) {
                    float a_[4];
                    #pragma unroll
                    for (int j = 0; j < 4; ++j) a_[j] = ddt[(ty * 4 + i) * 68 + tx * 4 + j];
                    float dg = diag_sh[ty * 4 + i];
                    float4 o;
                    o.x = a_[0] - dg; o.y = a_[1] - dg;
                    o.z = a_[2] - dg; o.w = a_[3] - dg;
                    *(float4*)&kb[(size_t)n * NHD + h * DD + tx * 4] = o;
                    km = fmaxf(km, fmaxf(fmaxf(a_[0], a_[1]), fmaxf(a_[2], a_[3])));
                }
            }
            #pragma unroll
            for (int off = 1; off < 64; off <<= 1) km = fmaxf(km, __shfl_xor(km, off, 64));
            if ((t & 63) == 0) wmax_sh[t >> 6] = km;
            __syncthreads();
            if (t == 0) {
                float m2 = fmaxf(fmaxf(wmax_sh[0], wmax_sh[1]), fmaxf(wmax_sh[2], wmax_sh[3]));
                atomicMax(&gmax[h], f2key(m2));
            }
        }
    }
}

// ---------------------------------------------------------------- K3: fused kp finalize + transpose
__global__ __launch_bounds__(256) void kfin_tr_kernel(
    const float* __restrict__ kb, const unsigned* __restrict__ gmax,
    unsigned short* __restrict__ kbh, unsigned short* __restrict__ kbhT) {
    __shared__ unsigned short tl[64][72];
    const int t = threadIdx.x;
    const int n0 = blockIdx.x * 64;
    const int h = blockIdx.y;
    const float mx = key2f(gmax[h]);
    const float4* s4 = (const float4*)kb;
    #pragma unroll
    for (int it = 0; it < 4; ++it) {
        int idx = t + it * 256;
        int n = idx >> 4, c4 = idx & 15;
        ushort4 u = make_ushort4(0, 0, 0, 0);
        if (n0 + n < NN) {
            float4 v = s4[(size_t)(n0 + n) * 64 + h * 16 + c4];
            u.x = f2bf(0.125f * (__expf(v.x - mx) + 1e-6f));
            u.y = f2bf(0.125f * (__expf(v.y - mx) + 1e-6f));
            u.z = f2bf(0.125f * (__expf(v.z - mx) + 1e-6f));
            u.w = f2bf(0.125f * (__expf(v.w - mx) + 1e-6f));
            *(ushort4*)&kbh[(size_t)(n0 + n) * NHD + h * DD + c4 * 4] = u;
        }
        tl[c4 * 4 + 0][n] = u.x;
        tl[c4 * 4 + 1][n] = u.y;
        tl[c4 * 4 + 2][n] = u.z;
        tl[c4 * 4 + 3][n] = u.w;
    }
    __syncthreads();
    uint4* d4 = (uint4*)kbhT;
    #pragma unroll
    for (int it = 0; it < 2; ++it) {
        int idx = t + it * 256;
        int m = idx >> 3, g = idx & 7;
        d4[(size_t)(h * 64 + m) * PITCH4 + (n0 >> 3) + g] = *(uint4*)&tl[m][g * 8];
    }
}

// ---------------------------------------------------------------- K3b: transpose bf16 [n][256] -> [h*64+c][n]
__global__ __launch_bounds__(256) void transp_bf16_kernel(
    const unsigned short* __restrict__ src, unsigned short* __restrict__ dst) {
    __shared__ unsigned short tl[64][72];
    const int t = threadIdx.x;
    const int nt = blockIdx.x * 64;
    const int h = blockIdx.y;
    const uint4* s4 = (const uint4*)src;
    #pragma unroll
    for (int it = 0; it < 2; ++it) {
        int idx = t + it * 256;
        int n = idx >> 3, g = idx & 7;
        uint4 v = make_uint4(0u, 0u, 0u, 0u);
        if (nt + n < NN) v = s4[(size_t)(nt + n) * 32 + h * 8 + g];
        const unsigned short* e = (const unsigned short*)&v;
        #pragma unroll
        for (int j = 0; j < 8; ++j) tl[g * 8 + j][n] = e[j];
    }
    __syncthreads();
    uint4* d4 = (uint4*)dst;
    #pragma unroll
    for (int it = 0; it < 2; ++it) {
        int idx = t + it * 256;
        int m = idx >> 3, g = idx & 7;
        d4[(size_t)(h * 64 + m) * PITCH4 + (nt >> 3) + g] = *(uint4*)&tl[m][g * 8];
    }
}

// ---------------------------------------------------------------- K3c: bf16 -> fp8 e4m3 (x2048) mirror
__global__ __launch_bounds__(256) void fp8cast_kernel(
    const unsigned short* __restrict__ src, unsigned char* __restrict__ dst) {
    int idx = blockIdx.x * 256 + threadIdx.x;   // 960,000 x 8 elems
    uint4 v = ((const uint4*)src)[idx];
    const unsigned short* e = (const unsigned short*)&v;
    unsigned char o[8];
    #pragma unroll
    for (int j = 0; j < 8; ++j) o[j] = ftofp8(bf2f(e[j]) * 2048.f);
    ((uint2*)dst)[idx] = *(uint2*)o;
}

// ---------------------------------------------------------------- K4: kvs via MFMA bf16 (2 subtiles/block, grid 250x4)
__global__ __launch_bounds__(512) void kvs_kernel(
    const unsigned short* __restrict__ kbhT, const unsigned short* __restrict__ vbhT,
    const float* __restrict__ gum,
    unsigned short* __restrict__ kvsp, float* __restrict__ ksp, float* __restrict__ ksump) {
    __shared__ __align__(16) unsigned short va [64 * 64];        //  8 KB
    __shared__ __align__(16) unsigned short kpw[KK][64 * 64];    // 48 KB
    __shared__ float w_sh[KK][256];                              //  6 KB
    const int c2 = blockIdx.x, h = blockIdx.y;
    const int c = c2 >> 1, z = c2 & 1;
    const int t = threadIdx.x;
    const int n0 = c * CHUNK;
    const int n1 = n0 + CHUNK;
    for (int i = t; i < 256; i += 512) {
        int n = n0 + i;
        bool ok = (i < CHUNK);
        #pragma unroll
        for (int k = 0; k < KK; ++k)
            w_sh[k][i] = ok ? __expf(gum[n * 24 + h * KK + k] * 4.0f) : 0.f;
    }
    const int m_ = t >> 3, g_ = t & 7;
    const int w = t >> 6, lane = t & 63, lrow = lane & 15, lk = lane >> 4;
    const int ds = w & 3, mh = w >> 2;
    const int arow = ds * 16 + lrow;
    f32x4 acc[KK][2];
    #pragma unroll
    for (int k = 0; k < KK; ++k) {
        acc[k][0] = (f32x4){0.f, 0.f, 0.f, 0.f};
        acc[k][1] = (f32x4){0.f, 0.f, 0.f, 0.f};
    }
    float ks_acc[KK] = {0.f, 0.f, 0.f, 0.f, 0.f, 0.f};
    float ksum_acc = 0.f;
    const uint4* kT4 = (const uint4*)kbhT;
    const uint4* vT4 = (const uint4*)vbhT;
    __syncthreads();   // w_sh ready
    for (int s = z * 2; s < z * 2 + 2; ++s) {
        const int nb = n0 + s * 64;
        uint4 kvv = kT4[(size_t)(h * 64 + m_) * PITCH4 + (nb >> 3) + g_];
        uint4 vvv = vT4[(size_t)(h * 64 + m_) * PITCH4 + (nb >> 3) + g_];
        const int slot = g_ ^ (m_ & 7);
        *(uint4*)&va[m_ * 64 + slot * 8] = vvv;
        float kf[8];
        {
            const unsigned short* ke = (const unsigned short*)&kvv;
            float sl = 0.f;
            int nbase = nb + g_ * 8;
            #pragma unroll
            for (int e = 0; e < 8; ++e) {
                kf[e] = bf2f(ke[e]);
                if (nbase + e < n1) sl += kf[e];
            }
            sl += __shfl_xor(sl, 1, 64);
            sl += __shfl_xor(sl, 2, 64);
            sl += __shfl_xor(sl, 4, 64);
            if (g_ == 0) ksum_acc += sl;
        }
        const int bw = s * 64;
        const int gg = g_ ^ (m_ & 7);
        #pragma unroll
        for (int k = 0; k < KK; ++k) {
            unsigned short ov[8];
            float sl = 0.f;
            #pragma unroll
            for (int e = 0; e < 8; ++e) {
                float p = kf[e] * w_sh[k][bw + gg * 8 + e];
                sl += p;
                ov[e] = f2bf(p);
            }
            *(uint4*)&kpw[k][m_ * 64 + g_ * 8] = *(uint4*)ov;
            sl += __shfl_xor(sl, 1, 64);
            sl += __shfl_xor(sl, 2, 64);
            sl += __shfl_xor(sl, 4, 64);
            if (g_ == 0) ks_acc[k] += sl;
        }
        __syncthreads();   // va + all 6 kpw staged
        bf16x8 a0 = *(const bf16x8*)&va[arow * 64 + ((lk ^ (arow & 7)) * 8)];
        bf16x8 a1 = *(const bf16x8*)&va[arow * 64 + (((lk + 4) ^ (arow & 7)) * 8)];
        #pragma unroll
        for (int k = 0; k < KK; ++k) {
            #pragma unroll
            for (int mt = 0; mt < 2; ++mt) {
                int m = (mh * 2 + mt) * 16 + lrow;
                bf16x8 b0 = *(const bf16x8*)&kpw[k][m * 64 + ((lk ^ (m & 7)) * 8)];
                bf16x8 b1 = *(const bf16x8*)&kpw[k][m * 64 + (((lk + 4) ^ (m & 7)) * 8)];
                acc[k][mt] = __builtin_amdgcn_mfma_f32_16x16x32_bf16(a0, b0, acc[k][mt], 0, 0, 0);
                acc[k][mt] = __builtin_amdgcn_mfma_f32_16x16x32_bf16(a1, b1, acc[k][mt], 0, 0, 0);
            }
        }
        __syncthreads();   // all reads done before next subtile overwrites
    }
    const size_t cb = (size_t)(c2 * HH + h) * KK;
    #pragma unroll
    for (int k = 0; k < KK; ++k)
        #pragma unroll
        for (int mt = 0; mt < 2; ++mt) {
            int m = (mh * 2 + mt) * 16 + lrow;
            #pragma unroll
            for (int r = 0; r < 4; ++r) {
                int d = ds * 16 + lk * 4 + r;
                kvsp[(cb + k) * 4096 + d * 64 + m] = f2bf(acc[k][mt][r]);
            }
        }
    if (g_ == 0) {
        #pragma unroll
        for (int k = 0; k < KK; ++k)
            ksp[(cb + k) * 64 + m_] = ks_acc[k];
        ksump[(size_t)(c2 * HH + h) * 64 + m_] = ksum_acc;
    }
}

// ---------------------------------------------------------------- K5: reduce bf16 partials
__global__ void reduce_kernel(const unsigned short* __restrict__ kvsp,
                              const float* __restrict__ ksp, const float* __restrict__ ksump,
                              unsigned short* __restrict__ kvshT, float* __restrict__ kss,
                              float* __restrict__ ksum) {
    int idx = blockIdx.x * 256 + threadIdx.x;
    if (idx < 98304) {
        float s = 0.f;
        for (int c = 0; c < NP; ++c) s += bf2f(kvsp[c * 98304 + idx]);
        kvshT[idx] = f2bf(s);
    } else if (idx < 98304 + 1536) {
        int o = idx - 98304;
        float s = 0.f;
        for (int c = 0; c < NP; ++c) s += ksp[c * 1536 + o];
        kss[o] = s;
    } else if (idx < 98304 + 1536 + 256) {
        int o = idx - 98304 - 1536;
        float s = 0.f;
        for (int c = 0; c < NP; ++c) s += ksump[c * 256 + o];
        ksum[o] = s;
    }
}

// ---------------------------------------------------------------- K6: znum via MFMA bf16 (512 thr, MFMA z_den)
__global__ __launch_bounds__(512) void znum_kernel(
    const unsigned short* __restrict__ qbh, const unsigned short* __restrict__ kvshT,
    const float* __restrict__ kss, const float* __restrict__ ksum,
    unsigned short* __restrict__ zouth, float* __restrict__ nrm) {
    __shared__ __align__(16) unsigned short qpa[64 * 64];   //  8 KB
    __shared__ __align__(16) unsigned short bt[6 * 64 * 64];// 48 KB
    __shared__ __align__(16) unsigned short bbuf[16 * 72];  // ks/ksum cols, padded
    __shared__ float zdi[64 * 6];
    const int t = threadIdx.x;
    const int h = blockIdx.y;
    const int n0 = blockIdx.x * 64;
    const uint4* qg = (const uint4*)qbh;
    {
        int row = t >> 3, c8 = t & 7;       // 512 items exactly
        int n = n0 + row;
        uint4 v = make_uint4(0u, 0u, 0u, 0u);
        if (n < NN) v = qg[n * 32 + h * 8 + c8];
        *(uint4*)&qpa[row * 64 + ((c8 ^ (row & 7)) * 8)] = v;
    }
    const uint4* bg = (const uint4*)kvshT;
    #pragma unroll
    for (int q = 0; q < 6; ++q) {
        int idx = t + q * 512;
        int kd = idx >> 3, c8 = idx & 7;
        *(uint4*)&bt[kd * 64 + ((c8 ^ (kd & 7)) * 8)] = bg[h * 3072 + idx];
    }
    #pragma unroll
    for (int q = 0; q < 2; ++q) {
        int idx = t + q * 512;              // 1024 = 16 cols x 64 m
        int col = idx >> 6, m = idx & 63;
        float v = 0.f;
        if (col < 6) v = kss[h * 384 + col * 64 + m];
        else if (col == 6) v = ksum[h * 64 + m];
        bbuf[col * 72 + m] = f2bf(v);
    }
    __syncthreads();
    const int w = t >> 6, lane = t & 63;
    const int lrow = lane & 15, lk = lane >> 4;
    const int w2 = w & 3, wh = w >> 2;
    const int arow = w2 * 16 + lrow;
    const int aswz = (arow & 7) << 3;
    bf16x8 a0 = *(const bf16x8*)&qpa[arow * 64 + ((lk * 8) ^ aswz)];
    bf16x8 a1 = *(const bf16x8*)&qpa[arow * 64 + ((lk * 8 + 32) ^ aswz)];
    // phase 1: z_den + nrm via one MFMA pair (waves wh==0 only).
    if (wh == 0) {
        bf16x8 b0 = *(const bf16x8*)&bbuf[lrow * 72 + lk * 8];
        bf16x8 b1 = *(const bf16x8*)&bbuf[lrow * 72 + lk * 8 + 32];
        f32x4 acc = {0.f, 0.f, 0.f, 0.f};
        acc = __builtin_amdgcn_mfma_f32_16x16x32_bf16(a0, b0, acc, 0, 0, 0);
        acc = __builtin_amdgcn_mfma_f32_16x16x32_bf16(a1, b1, acc, 0, 0, 0);
        #pragma unroll
        for (int r = 0; r < 4; ++r) {
            int node = w2 * 16 + lk * 4 + r;
            if (lrow < 6) zdi[node * 6 + lrow] = 1.0f / acc[r];
            else if (lrow == 6) {
                int n = n0 + node;
                if (n < NN) nrm[n * HH + h] = acc[r];
            }
        }
    }
    __syncthreads();
    const float inv6 = 1.0f / 6.0f;
    #pragma unroll
    for (int dtt = 0; dtt < 2; ++dtt) {
        const int dt = wh * 2 + dtt;
        f32x4 outv = {0.f, 0.f, 0.f, 0.f};
        #pragma unroll
        for (int k = 0; k < KK; ++k) {
            int kd = k * 64 + dt * 16 + lrow;
            int sw = (kd & 7) << 3;
            bf16x8 b0 = *(const bf16x8*)&bt[kd * 64 + ((lk * 8) ^ sw)];
            bf16x8 b1 = *(const bf16x8*)&bt[kd * 64 + ((lk * 8 + 32) ^ sw)];
            f32x4 acc = {0.f, 0.f, 0.f, 0.f};
            acc = __builtin_amdgcn_mfma_f32_16x16x32_bf16(a0, b0, acc, 0, 0, 0);
            acc = __builtin_amdgcn_mfma_f32_16x16x32_bf16(a1, b1, acc, 0, 0, 0);
            #pragma unroll
            for (int r = 0; r < 4; ++r)
                outv[r] += zdi[(w2 * 16 + lk * 4 + r) * 6 + k] * acc[r];
        }
        #pragma unroll
        for (int r = 0; r < 4; ++r) {
            int n = n0 + w2 * 16 + lk * 4 + r;
            if (n < NN) zouth[(size_t)n * NHD + h * DD + dt * 16 + lrow] = f2bf(outv[r] * inv6);
        }
    }
}

// ---------------------------------------------------------------- K7: output projection (bf16 in, f32 out)
__global__ __launch_bounds__(256) void outproj_kernel(
    const unsigned short* __restrict__ zouth, const float* __restrict__ Wo,
    const float* __restrict__ bo, float* __restrict__ out) {
    __shared__ float zsh[16][NHD];
    const int t = threadIdx.x;
    const int n0 = blockIdx.x * 16;
    const uint4* zg = (const uint4*)zouth;
    #pragma unroll
    for (int q = 0; q < 2; ++q) {
        int idx = t + q * 256;
        int row = idx >> 5, g = idx & 31;
        uint4 v = zg[(size_t)(n0 + row) * 32 + g];
        const unsigned short* e = (const unsigned short*)&v;
        #pragma unroll
        for (int j = 0; j < 8; ++j) zsh[row][g * 8 + j] = bf2f(e[j]);
    }
    __syncthreads();
    const int c = t & 63, g = t >> 6;
    float acc[4];
    #pragma unroll
    for (int i = 0; i < 4; ++i) acc[i] = bo[c];
    for (int r = 0; r < 256; ++r) {
        float w = Wo[r * 64 + c];
        #pragma unroll
        for (int i = 0; i < 4; ++i) acc[i] += zsh[g + 4 * i][r] * w;
    }
    #pragma unroll
    for (int i = 0; i < 4; ++i)
        out[(n0 + g + 4 * i) * 64 + c] = acc[i];
}

// ---------------------------------------------------------------- K8: edges, fp8 gather + HW decode
__global__ __launch_bounds__(256) void edge_fp8_kernel(
    const unsigned char* __restrict__ qb8, const unsigned char* __restrict__ kb8,
    const int* __restrict__ ei, const float* __restrict__ nrm,
    float* __restrict__ out) {
    const int t = threadIdx.x;
    const int li = t & 15;
    const int e = blockIdx.x * 16 + (t >> 4);
    const int s = ei[e], d = ei[EE + e];
    uint4 qv = ((const uint4*)qb8)[d * 16 + li];
    uint4 kv = ((const uint4*)kb8)[s * 16 + li];
    float qf[16], kf[16];
    fp8x4tof(qv.x, qf + 0);  fp8x4tof(qv.y, qf + 4);
    fp8x4tof(qv.z, qf + 8);  fp8x4tof(qv.w, qf + 12);
    fp8x4tof(kv.x, kf + 0);  fp8x4tof(kv.y, kf + 4);
    fp8x4tof(kv.z, kf + 8);  fp8x4tof(kv.w, kf + 12);
    float p = 0.f;
    #pragma unroll
    for (int i = 0; i < 16; ++i) p = fmaf(qf[i], kf[i], p);
    p += __shfl_xor(p, 1, 64);
    p += __shfl_xor(p, 2, 64);
    if ((li & 3) == 0) {
        int h = li >> 2;
        out[ZOFF + e * 4 + h] = p * (1.0f / (2048.f * 2048.f)) / nrm[d * HH + h];
    }
}

// ---------------------------------------------------------------- launch
extern "C" void kernel_launch(void* const* d_in, const int* in_sizes, int n_in,
                              void* d_out, int out_size, void* d_ws, size_t ws_size,
                              hipStream_t stream) {
    (void)in_sizes; (void)n_in; (void)out_size;
    const float* z  = (const float*)d_in[0];
    const float* Wq = (const float*)d_in[1];
    const float* bq = (const float*)d_in[2];
    const float* Wk = (const float*)d_in[3];
    const float* bk = (const float*)d_in[4];
    const float* Wv = (const float*)d_in[5];
    const float* bv = (const float*)d_in[6];
    const float* Wo = (const float*)d_in[7];
    const float* bo = (const float*)d_in[8];
    const float* proj = (const float*)d_in[9];
    const float* gum  = (const float*)d_in[10];
    const int*   ei   = (const int*)d_in[11];
    float* out = (float*)d_out;
    float* ws = (float*)d_ws;

    if (ws_size / 4 < (size_t)38673348) return;

    // region map (floats):
    // [0, 3.84M)       : zh (pre-qkv) -> qb8/kb8 (post-reduce)
    // [3.84M, 4.0M)    : WT (pre-qkv)
    // [4.0M, 16.29M)   : kvsp bf16 (NP=250 partials; kb/vh regions dead by kvs time)
    // [16.3M, 16.77M)  : ksp + ksump (dead before znum writes zouth)
    // [7.68M,15.36M)   : kb f32 (feat->kfin_tr, then dead)
    // [15.36M,19.2M)   : vh bf16 (qkv->transp) -> zouth bf16 (znum->outproj)
    // [23.04M ...)     : kvshT, projh, kss, ksum, nrm, gmax, qbh, kbh, kbhT, vbhT
    float* kb    = ws + 7680000;
    unsigned short* zouth = (unsigned short*)(ws + 15360000);
    unsigned short* vh = (unsigned short*)(ws + 15360000);
    unsigned short* kvshT = (unsigned short*)(ws + 23040000);
    unsigned short* projh = (unsigned short*)(ws + 23089152);
    float* kss   = ws + 23138304;
    float* ksum  = ws + 23139840;
    float* nrm   = ws + 23140096;
    unsigned* gmax = (unsigned*)(ws + 23260096);
    unsigned short* qbh = (unsigned short*)(ws + 23260100);
    unsigned short* kbh = (unsigned short*)(ws + 27100100);
    unsigned short* kbhT = (unsigned short*)(ws + 30940100);
    unsigned short* vbhT = (unsigned short*)(ws + 34806724);
    unsigned short* zh = (unsigned short*)ws;                  // dead after qkv
    unsigned short* WT = (unsigned short*)(ws + 3840000);      // dead after qkv
    unsigned short* kvsp = (unsigned short*)(ws + 4000000);    // NP*98304 bf16
    float* ksp   = ws + 16300000;                              // NP*1536
    float* ksump = ws + 16700000;                              // NP*256
    unsigned char* qb8 = (unsigned char*)ws;                   // post-reduce alias
    unsigned char* kb8 = (unsigned char*)(ws + 1920000);

    init_kernel<<<1, 64, 0, stream>>>(gmax);
    zcast_kernel<<<3750, 256, 0, stream>>>(z, zh);
    wtransp_kernel<<<dim3(8, 3), 256, 0, stream>>>(Wq, Wk, Wv, WT);
    projcast_kernel<<<16, 256, 0, stream>>>(proj, projh);
    qkv_mfma_kernel<<<dim3(235, 3), 256, 0, stream>>>(zh, WT, bq, bk, bv, qbh, kbh, vh);
    transp_bf16_kernel<<<dim3(472, HH), 256, 0, stream>>>(vh, vbhT);
    feat_mfma_kernel<<<dim3(469, HH), 256, 0, stream>>>(qbh, kbh, kb, projh, gmax);
    kfin_tr_kernel<<<dim3(472, HH), 256, 0, stream>>>(kb, gmax, kbh, kbhT);
    kvs_kernel<<<dim3(NP, HH), 512, 0, stream>>>(kbhT, vbhT, gum, kvsp, ksp, ksump);
    reduce_kernel<<<392, 256, 0, stream>>>(kvsp, ksp, ksump, kvshT, kss, ksum);
    fp8cast_kernel<<<3750, 256, 0, stream>>>(qbh, qb8);
    fp8cast_kernel<<<3750, 256, 0, stream>>>(kbh, kb8);
    znum_kernel<<<dim3(469, HH), 512, 0, stream>>>(qbh, kvshT, kss, ksum, zouth, nrm);
    outproj_kernel<<<1875, 256, 0, stream>>>(zouth, Wo, bo, out);
    edge_fp8_kernel<<<30000, 256, 0, stream>>>(qb8, kb8, ei, nrm, out);
}

// Round 20
// 206.804 us; speedup vs baseline: 1.0843x; 1.0843x over previous
//
#include <hip/hip_runtime.h>
#include <hip/hip_bf16.h>

#define NN   30000
#define DIN  128
#define NHD  256      // H*D
#define HH   4
#define DD   64
#define MM   64
#define KK   6
#define EE   480000
#define ZOFF 1920000  // 30000*64
#define NCS   125
#define CHUNK 240
#define PITCH  30208   // padded bf16 elems per row of kbhT/vbhT
#define PITCH4 3776    // uint4 per row

typedef __attribute__((ext_vector_type(8))) short bf16x8;
typedef __attribute__((ext_vector_type(4))) float f32x4;
typedef __attribute__((ext_vector_type(2))) float f32x2;

__device__ __forceinline__ unsigned f2key(float f) {
    unsigned u = __float_as_uint(f);
    return (u & 0x80000000u) ? ~u : (u | 0x80000000u);
}
__device__ __forceinline__ float key2f(unsigned k) {
    return __uint_as_float((k & 0x80000000u) ? (k ^ 0x80000000u) : ~k);
}
__device__ __forceinline__ unsigned short f2bf(float f) {   // RNE
    unsigned u = __float_as_uint(f);
    unsigned r = ((u >> 16) & 1u) + 0x7fffu;
    return (unsigned short)((u + r) >> 16);
}
__device__ __forceinline__ float bf2f(unsigned short u) {
    return __uint_as_float((unsigned)u << 16);
}
// fp8 e4m3fn, POSITIVE values only, RNE, satfinite
__device__ __forceinline__ unsigned char ftofp8(float x) {
    unsigned u = __float_as_uint(x);
    int e32 = (int)(u >> 23) - 127;
    if (e32 <= -7) {                       // subnormal target (x < 2^-6)
        int m = (int)rintf(x * 512.f);     // RNE; m in [0,8]; m==8 == 2^-6 encoding
        return (unsigned char)m;
    }
    unsigned r = ((u >> 20) & 1u) + 0x7FFFFu;
    u += r;
    e32 = (int)(u >> 23) - 127;
    if (e32 > 8) return 0x7E;              // 448
    int m = (u >> 20) & 7;
    return (unsigned char)(((e32 + 7) << 3) | m);
}
__device__ __forceinline__ float fp8tof(unsigned char u) {
    int e = (u >> 3) & 15, m = u & 7;
    if (e == 0) return (float)m * 0.001953125f;              // m * 2^-9
    return __uint_as_float((unsigned)((e + 120) << 23) | ((unsigned)m << 20));
}
// decode 4 fp8 bytes of a uint -> 4 floats (HW converter when available)
__device__ __forceinline__ void fp8x4tof(unsigned w, float* o) {
#if __has_builtin(__builtin_amdgcn_cvt_pk_f32_fp8)
    f32x2 lo = __builtin_amdgcn_cvt_pk_f32_fp8((int)w, false);
    f32x2 hi = __builtin_amdgcn_cvt_pk_f32_fp8((int)w, true);
    o[0] = lo[0]; o[1] = lo[1]; o[2] = hi[0]; o[3] = hi[1];
#else
    o[0] = fp8tof((unsigned char)(w & 255));
    o[1] = fp8tof((unsigned char)((w >> 8) & 255));
    o[2] = fp8tof((unsigned char)((w >> 16) & 255));
    o[3] = fp8tof((unsigned char)((w >> 24) & 255));
#endif
}

// ---------------------------------------------------------------- init
__global__ void init_kernel(unsigned* gmax) {
    if (threadIdx.x < HH) gmax[threadIdx.x] = 0u;
}

// ---------------------------------------------------------------- K0a: z -> bf16
__global__ __launch_bounds__(256) void zcast_kernel(
    const float* __restrict__ z, unsigned short* __restrict__ zh) {
    int idx = blockIdx.x * 256 + threadIdx.x;   // 960,000 float4 exactly
    float4 v = ((const float4*)z)[idx];
    ushort4 u;
    u.x = f2bf(v.x); u.y = f2bf(v.y); u.z = f2bf(v.z); u.w = f2bf(v.w);
    ((ushort4*)zh)[idx] = u;
}

// ---------------------------------------------------------------- K0b: W [128][256] -> WT bf16 [256][128]
__global__ __launch_bounds__(256) void wtransp_kernel(
    const float* __restrict__ Wq, const float* __restrict__ Wk,
    const float* __restrict__ Wv, unsigned short* __restrict__ WT) {
    __shared__ unsigned short tl[64][72];
    const int t = threadIdx.x;
    const int kt = blockIdx.x & 1, ct = blockIdx.x >> 1;
    const int wi = blockIdx.y;
    const float* W = (wi == 0) ? Wq : (wi == 1) ? Wk : Wv;
    const float4* W4 = (const float4*)W;
    #pragma unroll
    for (int it = 0; it < 4; ++it) {
        int idx = t + it * 256;
        int r = idx >> 4, c4 = idx & 15;
        float4 v = W4[(kt * 64 + r) * 64 + ct * 16 + c4];
        tl[c4 * 4 + 0][r] = f2bf(v.x);
        tl[c4 * 4 + 1][r] = f2bf(v.y);
        tl[c4 * 4 + 2][r] = f2bf(v.z);
        tl[c4 * 4 + 3][r] = f2bf(v.w);
    }
    __syncthreads();
    uint4* d4 = (uint4*)WT;
    #pragma unroll
    for (int it = 0; it < 2; ++it) {
        int idx = t + it * 256;
        int m = idx >> 3, g = idx & 7;
        d4[((size_t)wi * 256 + ct * 64 + m) * 16 + kt * 8 + g] = *(uint4*)&tl[m][g * 8];
    }
}

// ---------------------------------------------------------------- K0c: proj*dn -> bf16
__global__ void projcast_kernel(const float* __restrict__ proj,
                                unsigned short* __restrict__ projh) {
    int i = blockIdx.x * 256 + threadIdx.x;   // 4096 exactly
    projh[i] = f2bf(proj[i] * 0.35355339059327373f);
}

// ---------------------------------------------------------------- K1: qkv via MFMA bf16, bf16 outputs
__global__ __launch_bounds__(256) void qkv_mfma_kernel(
    const unsigned short* __restrict__ zh, const unsigned short* __restrict__ WT,
    const float* __restrict__ bq, const float* __restrict__ bk, const float* __restrict__ bv,
    unsigned short* __restrict__ qh, unsigned short* __restrict__ kh,
    unsigned short* __restrict__ vh) {
    __shared__ __align__(16) unsigned short zt[128 * 128];
    __shared__ __align__(16) unsigned short wt[64 * 128];
    const int t = threadIdx.x;
    const int n0 = blockIdx.x * 128;
    const int wi = blockIdx.y;
    const float sc = (wi == 2) ? 1.0f : 2.0f;
    const float* bias = (wi == 0) ? bq : (wi == 1) ? bk : bv;
    unsigned short* outp = (wi == 0) ? qh : (wi == 1) ? kh : vh;
    const uint4* zg = (const uint4*)zh;
    #pragma unroll
    for (int it = 0; it < 8; ++it) {
        int idx = t + it * 256;
        int row = idx >> 4, g = idx & 15;
        int n = n0 + row;
        uint4 v = make_uint4(0u, 0u, 0u, 0u);
        if (n < NN) v = zg[(size_t)n * 16 + g];
        *(uint4*)&zt[row * 128 + ((g ^ (row & 7)) * 8)] = v;
    }
    const uint4* wg = (const uint4*)WT + (size_t)wi * 4096;
    const int w = t >> 6, lane = t & 63, lrow = lane & 15, lk = lane >> 4;
    for (int cc = 0; cc < 4; ++cc) {
        __syncthreads();
        #pragma unroll
        for (int it = 0; it < 4; ++it) {
            int idx = t + it * 256;
            int r = idx >> 4, g = idx & 15;
            *(uint4*)&wt[r * 128 + ((g ^ (r & 7)) * 8)] = wg[(cc * 64 + r) * 16 + g];
        }
        __syncthreads();
        f32x4 acc[4][2];
        #pragma unroll
        for (int mt = 0; mt < 4; ++mt) {
            acc[mt][0] = (f32x4){0.f, 0.f, 0.f, 0.f};
            acc[mt][1] = (f32x4){0.f, 0.f, 0.f, 0.f};
        }
        #pragma unroll
        for (int ks = 0; ks < 4; ++ks) {
            const int g0 = ks * 4 + lk;
            bf16x8 a[4], b[2];
            #pragma unroll
            for (int mt = 0; mt < 4; ++mt) {
                int r = mt * 16 + lrow;
                a[mt] = *(const bf16x8*)&wt[r * 128 + ((g0 ^ (r & 7)) * 8)];
            }
            #pragma unroll
            for (int nt = 0; nt < 2; ++nt) {
                int node = (w * 2 + nt) * 16 + lrow;
                b[nt] = *(const bf16x8*)&zt[node * 128 + ((g0 ^ (node & 7)) * 8)];
            }
            #pragma unroll
            for (int mt = 0; mt < 4; ++mt)
                #pragma unroll
                for (int nt = 0; nt < 2; ++nt)
                    acc[mt][nt] = __builtin_amdgcn_mfma_f32_16x16x32_bf16(
                        a[mt], b[nt], acc[mt][nt], 0, 0, 0);
        }
        #pragma unroll
        for (int mt = 0; mt < 4; ++mt) {
            int cbase = cc * 64 + mt * 16 + lk * 4;
            float4 bi = *(const float4*)&bias[cbase];
            #pragma unroll
            for (int nt = 0; nt < 2; ++nt) {
                int n = n0 + (w * 2 + nt) * 16 + lrow;
                if (n < NN) {
                    ushort4 u;
                    u.x = f2bf((acc[mt][nt][0] + bi.x) * sc);
                    u.y = f2bf((acc[mt][nt][1] + bi.y) * sc);
                    u.z = f2bf((acc[mt][nt][2] + bi.z) * sc);
                    u.w = f2bf((acc[mt][nt][3] + bi.w) * sc);
                    *(ushort4*)&outp[(size_t)n * NHD + cbase] = u;
                }
            }
        }
    }
}

// ---------------------------------------------------------------- K2: random features via MFMA (+ fused fp8 qp)
__global__ __launch_bounds__(256) void feat_mfma_kernel(
    unsigned short* __restrict__ qbh, const unsigned short* __restrict__ kh,
    float* __restrict__ kb, const unsigned short* __restrict__ projh,
    unsigned* __restrict__ gmax, unsigned char* __restrict__ qb8) {
    __shared__ __align__(16) unsigned short at[64 * 64];
    __shared__ __align__(16) unsigned short pb[64 * 64];
    __shared__ __align__(16) float ddt[64 * 68];
    __shared__ float diag_sh[64];
    __shared__ float wmax_sh[4];
    const int t = threadIdx.x;
    const int h = blockIdx.y;
    const int n0 = blockIdx.x * 64;
    const int tx = t & 15, ty = t >> 4;
    const uint4* pg = (const uint4*)projh;
    #pragma unroll
    for (int q = 0; q < 2; ++q) {
        int idx = t + q * 256;
        int m = idx >> 3, g = idx & 7;
        *(uint4*)&pb[m * 64 + ((g ^ (m & 7)) * 8)] = pg[idx];
    }
    const int w = t >> 6, lane = t & 63, lrow = lane & 15, lk = lane >> 4;
    const int arow = w * 16 + lrow;
    #pragma unroll
    for (int pass = 0; pass < 2; ++pass) {
        const uint4* src = (const uint4*)(pass ? kh : qbh);
        __syncthreads();
        #pragma unroll
        for (int q = 0; q < 2; ++q) {
            int idx = t + q * 256;
            int n = idx >> 3, g = idx & 7;
            uint4 v = make_uint4(0u, 0u, 0u, 0u);
            if (n0 + n < NN) v = src[(size_t)(n0 + n) * 32 + h * 8 + g];
            *(uint4*)&at[n * 64 + ((g ^ (n & 7)) * 8)] = v;
            const unsigned short* e8 = (const unsigned short*)&v;
            float ss = 0.f;
            #pragma unroll
            for (int j2 = 0; j2 < 8; ++j2) { float f = bf2f(e8[j2]); ss += f * f; }
            ss += __shfl_xor(ss, 1, 64);
            ss += __shfl_xor(ss, 2, 64);
            ss += __shfl_xor(ss, 4, 64);
            if (g == 0) diag_sh[n] = 0.0625f * ss;   // 0.5 * dn^2 * sum
        }
        __syncthreads();
        bf16x8 a0 = *(const bf16x8*)&at[arow * 64 + ((lk ^ (arow & 7)) * 8)];
        bf16x8 a1 = *(const bf16x8*)&at[arow * 64 + (((lk + 4) ^ (arow & 7)) * 8)];
        #pragma unroll
        for (int ct = 0; ct < 4; ++ct) {
            int brow = ct * 16 + lrow;
            bf16x8 b0 = *(const bf16x8*)&pb[brow * 64 + ((lk ^ (brow & 7)) * 8)];
            bf16x8 b1 = *(const bf16x8*)&pb[brow * 64 + (((lk + 4) ^ (brow & 7)) * 8)];
            f32x4 acc = {0.f, 0.f, 0.f, 0.f};
            acc = __builtin_amdgcn_mfma_f32_16x16x32_bf16(a0, b0, acc, 0, 0, 0);
            acc = __builtin_amdgcn_mfma_f32_16x16x32_bf16(a1, b1, acc, 0, 0, 0);
            #pragma unroll
            for (int r = 0; r < 4; ++r)
                ddt[(w * 16 + lk * 4 + r) * 68 + ct * 16 + lrow] = acc[r];
        }
        __syncthreads();
        if (pass == 0) {
            #pragma unroll
            for (int i = 0; i < 4; ++i) {
                int n = n0 + ty * 4 + i;
                float a_[4];
                #pragma unroll
                for (int j = 0; j < 4; ++j) a_[j] = ddt[(ty * 4 + i) * 68 + tx * 4 + j];
                float mx = fmaxf(fmaxf(a_[0], a_[1]), fmaxf(a_[2], a_[3]));
                mx = fmaxf(mx, __shfl_xor(mx, 1, 64));
                mx = fmaxf(mx, __shfl_xor(mx, 2, 64));
                mx = fmaxf(mx, __shfl_xor(mx, 4, 64));
                mx = fmaxf(mx, __shfl_xor(mx, 8, 64));
                if (n < NN) {
                    float dg = diag_sh[ty * 4 + i] + mx;
                    ushort4 u;
                    u.x = f2bf(0.125f * (__expf(a_[0] - dg) + 1e-6f));
                    u.y = f2bf(0.125f * (__expf(a_[1] - dg) + 1e-6f));
                    u.z = f2bf(0.125f * (__expf(a_[2] - dg) + 1e-6f));
                    u.w = f2bf(0.125f * (__expf(a_[3] - dg) + 1e-6f));
                    *(ushort4*)&qbh[(size_t)n * NHD + h * DD + tx * 4] = u;
                    uchar4 b8;
                    b8.x = ftofp8(bf2f(u.x) * 2048.f);
                    b8.y = ftofp8(bf2f(u.y) * 2048.f);
                    b8.z = ftofp8(bf2f(u.z) * 2048.f);
                    b8.w = ftofp8(bf2f(u.w) * 2048.f);
                    *(uchar4*)&qb8[(size_t)n * NHD + h * DD + tx * 4] = b8;
                }
            }
        } else {
            float km = -3.4e38f;
            #pragma unroll
            for (int i = 0; i < 4; ++i) {
                int n = n0 + ty * 4 + i;
                if (n < NN) {
                    float a_[4];
                    #pragma unroll
                    for (int j = 0; j < 4; ++j) a_[j] = ddt[(ty * 4 + i) * 68 + tx * 4 + j];
                    float dg = diag_sh[ty * 4 + i];
                    float4 o;
                    o.x = a_[0] - dg; o.y = a_[1] - dg;
                    o.z = a_[2] - dg; o.w = a_[3] - dg;
                    *(float4*)&kb[(size_t)n * NHD + h * DD + tx * 4] = o;
                    km = fmaxf(km, fmaxf(fmaxf(a_[0], a_[1]), fmaxf(a_[2], a_[3])));
                }
            }
            #pragma unroll
            for (int off = 1; off < 64; off <<= 1) km = fmaxf(km, __shfl_xor(km, off, 64));
            if ((t & 63) == 0) wmax_sh[t >> 6] = km;
            __syncthreads();
            if (t == 0) {
                float m2 = fmaxf(fmaxf(wmax_sh[0], wmax_sh[1]), fmaxf(wmax_sh[2], wmax_sh[3]));
                atomicMax(&gmax[h], f2key(m2));
            }
        }
    }
}

// ---------------------------------------------------------------- K3: fused kp finalize + transpose + fp8
__global__ __launch_bounds__(256) void kfin_tr_kernel(
    const float* __restrict__ kb, const unsigned* __restrict__ gmax,
    unsigned short* __restrict__ kbh, unsigned short* __restrict__ kbhT,
    unsigned char* __restrict__ kb8) {
    __shared__ unsigned short tl[64][72];
    const int t = threadIdx.x;
    const int n0 = blockIdx.x * 64;
    const int h = blockIdx.y;
    const float mx = key2f(gmax[h]);
    const float4* s4 = (const float4*)kb;
    #pragma unroll
    for (int it = 0; it < 4; ++it) {
        int idx = t + it * 256;
        int n = idx >> 4, c4 = idx & 15;
        ushort4 u = make_ushort4(0, 0, 0, 0);
        if (n0 + n < NN) {
            float4 v = s4[(size_t)(n0 + n) * 64 + h * 16 + c4];
            u.x = f2bf(0.125f * (__expf(v.x - mx) + 1e-6f));
            u.y = f2bf(0.125f * (__expf(v.y - mx) + 1e-6f));
            u.z = f2bf(0.125f * (__expf(v.z - mx) + 1e-6f));
            u.w = f2bf(0.125f * (__expf(v.w - mx) + 1e-6f));
            *(ushort4*)&kbh[(size_t)(n0 + n) * NHD + h * DD + c4 * 4] = u;
            uchar4 b8;
            b8.x = ftofp8(bf2f(u.x) * 2048.f);
            b8.y = ftofp8(bf2f(u.y) * 2048.f);
            b8.z = ftofp8(bf2f(u.z) * 2048.f);
            b8.w = ftofp8(bf2f(u.w) * 2048.f);
            *(uchar4*)&kb8[(size_t)(n0 + n) * NHD + h * DD + c4 * 4] = b8;
        }
        tl[c4 * 4 + 0][n] = u.x;
        tl[c4 * 4 + 1][n] = u.y;
        tl[c4 * 4 + 2][n] = u.z;
        tl[c4 * 4 + 3][n] = u.w;
    }
    __syncthreads();
    uint4* d4 = (uint4*)kbhT;
    #pragma unroll
    for (int it = 0; it < 2; ++it) {
        int idx = t + it * 256;
        int m = idx >> 3, g = idx & 7;
        d4[(size_t)(h * 64 + m) * PITCH4 + (n0 >> 3) + g] = *(uint4*)&tl[m][g * 8];
    }
}

// ---------------------------------------------------------------- K3b: transpose bf16 [n][256] -> [h*64+c][n]
__global__ __launch_bounds__(256) void transp_bf16_kernel(
    const unsigned short* __restrict__ src, unsigned short* __restrict__ dst) {
    __shared__ unsigned short tl[64][72];
    const int t = threadIdx.x;
    const int nt = blockIdx.x * 64;
    const int h = blockIdx.y;
    const uint4* s4 = (const uint4*)src;
    #pragma unroll
    for (int it = 0; it < 2; ++it) {
        int idx = t + it * 256;
        int n = idx >> 3, g = idx & 7;
        uint4 v = make_uint4(0u, 0u, 0u, 0u);
        if (nt + n < NN) v = s4[(size_t)(nt + n) * 32 + h * 8 + g];
        const unsigned short* e = (const unsigned short*)&v;
        #pragma unroll
        for (int j = 0; j < 8; ++j) tl[g * 8 + j][n] = e[j];
    }
    __syncthreads();
    uint4* d4 = (uint4*)dst;
    #pragma unroll
    for (int it = 0; it < 2; ++it) {
        int idx = t + it * 256;
        int m = idx >> 3, g = idx & 7;
        d4[(size_t)(h * 64 + m) * PITCH4 + (nt >> 3) + g] = *(uint4*)&tl[m][g * 8];
    }
}

// ---------------------------------------------------------------- K4: kvs via MFMA bf16 (hoisted kpw, NCS grid)
__global__ __launch_bounds__(512) void kvs_kernel(
    const unsigned short* __restrict__ kbhT, const unsigned short* __restrict__ vbhT,
    const float* __restrict__ gum,
    unsigned short* __restrict__ kvsp, float* __restrict__ ksp, float* __restrict__ ksump) {
    __shared__ __align__(16) unsigned short va [64 * 64];        //  8 KB
    __shared__ __align__(16) unsigned short kpw[KK][64 * 64];    // 48 KB
    __shared__ float w_sh[KK][256];                              //  6 KB
    const int c = blockIdx.x, h = blockIdx.y;
    const int t = threadIdx.x;
    const int n0 = c * CHUNK;
    const int n1 = n0 + CHUNK;
    for (int i = t; i < 256; i += 512) {
        int n = n0 + i;
        bool ok = (i < CHUNK);
        #pragma unroll
        for (int k = 0; k < KK; ++k)
            w_sh[k][i] = ok ? __expf(gum[n * 24 + h * KK + k] * 4.0f) : 0.f;
    }
    const int m_ = t >> 3, g_ = t & 7;
    const int w = t >> 6, lane = t & 63, lrow = lane & 15, lk = lane >> 4;
    const int ds = w & 3, mh = w >> 2;
    const int arow = ds * 16 + lrow;
    f32x4 acc[KK][2];
    #pragma unroll
    for (int k = 0; k < KK; ++k) {
        acc[k][0] = (f32x4){0.f, 0.f, 0.f, 0.f};
        acc[k][1] = (f32x4){0.f, 0.f, 0.f, 0.f};
    }
    float ks_acc[KK] = {0.f, 0.f, 0.f, 0.f, 0.f, 0.f};
    float ksum_acc = 0.f;
    const uint4* kT4 = (const uint4*)kbhT;
    const uint4* vT4 = (const uint4*)vbhT;
    __syncthreads();   // w_sh ready
    #pragma unroll
    for (int s = 0; s < 4; ++s) {
        const int nb = n0 + s * 64;
        uint4 kvv = kT4[(size_t)(h * 64 + m_) * PITCH4 + (nb >> 3) + g_];
        uint4 vvv = vT4[(size_t)(h * 64 + m_) * PITCH4 + (nb >> 3) + g_];
        const int slot = g_ ^ (m_ & 7);
        *(uint4*)&va[m_ * 64 + slot * 8] = vvv;
        float kf[8];
        {
            const unsigned short* ke = (const unsigned short*)&kvv;
            float sl = 0.f;
            int nbase = nb + g_ * 8;
            #pragma unroll
            for (int e = 0; e < 8; ++e) {
                kf[e] = bf2f(ke[e]);
                if (nbase + e < n1) sl += kf[e];
            }
            sl += __shfl_xor(sl, 1, 64);
            sl += __shfl_xor(sl, 2, 64);
            sl += __shfl_xor(sl, 4, 64);
            if (g_ == 0) ksum_acc += sl;
        }
        const int bw = s * 64;
        const int gg = g_ ^ (m_ & 7);
        #pragma unroll
        for (int k = 0; k < KK; ++k) {
            unsigned short ov[8];
            float sl = 0.f;
            #pragma unroll
            for (int e = 0; e < 8; ++e) {
                float p = kf[e] * w_sh[k][bw + gg * 8 + e];
                sl += p;
                ov[e] = f2bf(p);
            }
            *(uint4*)&kpw[k][m_ * 64 + g_ * 8] = *(uint4*)ov;
            sl += __shfl_xor(sl, 1, 64);
            sl += __shfl_xor(sl, 2, 64);
            sl += __shfl_xor(sl, 4, 64);
            if (g_ == 0) ks_acc[k] += sl;
        }
        __syncthreads();   // va + all 6 kpw staged
        bf16x8 a0 = *(const bf16x8*)&va[arow * 64 + ((lk ^ (arow & 7)) * 8)];
        bf16x8 a1 = *(const bf16x8*)&va[arow * 64 + (((lk + 4) ^ (arow & 7)) * 8)];
        #pragma unroll
        for (int k = 0; k < KK; ++k) {
            #pragma unroll
            for (int mt = 0; mt < 2; ++mt) {
                int m = (mh * 2 + mt) * 16 + lrow;
                bf16x8 b0 = *(const bf16x8*)&kpw[k][m * 64 + ((lk ^ (m & 7)) * 8)];
                bf16x8 b1 = *(const bf16x8*)&kpw[k][m * 64 + (((lk + 4) ^ (m & 7)) * 8)];
                acc[k][mt] = __builtin_amdgcn_mfma_f32_16x16x32_bf16(a0, b0, acc[k][mt], 0, 0, 0);
                acc[k][mt] = __builtin_amdgcn_mfma_f32_16x16x32_bf16(a1, b1, acc[k][mt], 0, 0, 0);
            }
        }
        __syncthreads();   // all reads done before next subtile overwrites
    }
    const size_t cb = (size_t)(c * HH + h) * KK;
    #pragma unroll
    for (int k = 0; k < KK; ++k)
        #pragma unroll
        for (int mt = 0; mt < 2; ++mt) {
            int m = (mh * 2 + mt) * 16 + lrow;
            #pragma unroll
            for (int r = 0; r < 4; ++r) {
                int d = ds * 16 + lk * 4 + r;
                kvsp[(cb + k) * 4096 + d * 64 + m] = f2bf(acc[k][mt][r]);
            }
        }
    if (g_ == 0) {
        #pragma unroll
        for (int k = 0; k < KK; ++k)
            ksp[(cb + k) * 64 + m_] = ks_acc[k];
        ksump[(size_t)(c * HH + h) * 64 + m_] = ksum_acc;
    }
}

// ---------------------------------------------------------------- K5: reduce bf16 partials
__global__ void reduce_kernel(const unsigned short* __restrict__ kvsp,
                              const float* __restrict__ ksp, const float* __restrict__ ksump,
                              unsigned short* __restrict__ kvshT, float* __restrict__ kss,
                              float* __restrict__ ksum) {
    int idx = blockIdx.x * 256 + threadIdx.x;
    if (idx < 98304) {
        float s = 0.f;
        for (int c = 0; c < NCS; ++c) s += bf2f(kvsp[c * 98304 + idx]);
        kvshT[idx] = f2bf(s);
    } else if (idx < 98304 + 1536) {
        int o = idx - 98304;
        float s = 0.f;
        for (int c = 0; c < NCS; ++c) s += ksp[c * 1536 + o];
        kss[o] = s;
    } else if (idx < 98304 + 1536 + 256) {
        int o = idx - 98304 - 1536;
        float s = 0.f;
        for (int c = 0; c < NCS; ++c) s += ksump[c * 256 + o];
        ksum[o] = s;
    }
}

// ---------------------------------------------------------------- K6: znum via MFMA bf16 (512 thr, MFMA z_den)
__global__ __launch_bounds__(512) void znum_kernel(
    const unsigned short* __restrict__ qbh, const unsigned short* __restrict__ kvshT,
    const float* __restrict__ kss, const float* __restrict__ ksum,
    unsigned short* __restrict__ zouth, float* __restrict__ nrm) {
    __shared__ __align__(16) unsigned short qpa[64 * 64];   //  8 KB
    __shared__ __align__(16) unsigned short bt[6 * 64 * 64];// 48 KB
    __shared__ __align__(16) unsigned short bbuf[16 * 72];  // ks/ksum cols, padded
    __shared__ float zdi[64 * 6];
    const int t = threadIdx.x;
    const int h = blockIdx.y;
    const int n0 = blockIdx.x * 64;
    const uint4* qg = (const uint4*)qbh;
    {
        int row = t >> 3, c8 = t & 7;       // 512 items exactly
        int n = n0 + row;
        uint4 v = make_uint4(0u, 0u, 0u, 0u);
        if (n < NN) v = qg[n * 32 + h * 8 + c8];
        *(uint4*)&qpa[row * 64 + ((c8 ^ (row & 7)) * 8)] = v;
    }
    const uint4* bg = (const uint4*)kvshT;
    #pragma unroll
    for (int q = 0; q < 6; ++q) {
        int idx = t + q * 512;
        int kd = idx >> 3, c8 = idx & 7;
        *(uint4*)&bt[kd * 64 + ((c8 ^ (kd & 7)) * 8)] = bg[h * 3072 + idx];
    }
    #pragma unroll
    for (int q = 0; q < 2; ++q) {
        int idx = t + q * 512;              // 1024 = 16 cols x 64 m
        int col = idx >> 6, m = idx & 63;
        float v = 0.f;
        if (col < 6) v = kss[h * 384 + col * 64 + m];
        else if (col == 6) v = ksum[h * 64 + m];
        bbuf[col * 72 + m] = f2bf(v);
    }
    __syncthreads();
    const int w = t >> 6, lane = t & 63;
    const int lrow = lane & 15, lk = lane >> 4;
    const int w2 = w & 3, wh = w >> 2;
    const int arow = w2 * 16 + lrow;
    const int aswz = (arow & 7) << 3;
    bf16x8 a0 = *(const bf16x8*)&qpa[arow * 64 + ((lk * 8) ^ aswz)];
    bf16x8 a1 = *(const bf16x8*)&qpa[arow * 64 + ((lk * 8 + 32) ^ aswz)];
    // phase 1: z_den + nrm via one MFMA pair (waves wh==0 only).
    if (wh == 0) {
        bf16x8 b0 = *(const bf16x8*)&bbuf[lrow * 72 + lk * 8];
        bf16x8 b1 = *(const bf16x8*)&bbuf[lrow * 72 + lk * 8 + 32];
        f32x4 acc = {0.f, 0.f, 0.f, 0.f};
        acc = __builtin_amdgcn_mfma_f32_16x16x32_bf16(a0, b0, acc, 0, 0, 0);
        acc = __builtin_amdgcn_mfma_f32_16x16x32_bf16(a1, b1, acc, 0, 0, 0);
        #pragma unroll
        for (int r = 0; r < 4; ++r) {
            int node = w2 * 16 + lk * 4 + r;
            if (lrow < 6) zdi[node * 6 + lrow] = 1.0f / acc[r];
            else if (lrow == 6) {
                int n = n0 + node;
                if (n < NN) nrm[n * HH + h] = acc[r];
            }
        }
    }
    __syncthreads();
    const float inv6 = 1.0f / 6.0f;
    #pragma unroll
    for (int dtt = 0; dtt < 2; ++dtt) {
        const int dt = wh * 2 + dtt;
        f32x4 outv = {0.f, 0.f, 0.f, 0.f};
        #pragma unroll
        for (int k = 0; k < KK; ++k) {
            int kd = k * 64 + dt * 16 + lrow;
            int sw = (kd & 7) << 3;
            bf16x8 b0 = *(const bf16x8*)&bt[kd * 64 + ((lk * 8) ^ sw)];
            bf16x8 b1 = *(const bf16x8*)&bt[kd * 64 + ((lk * 8 + 32) ^ sw)];
            f32x4 acc = {0.f, 0.f, 0.f, 0.f};
            acc = __builtin_amdgcn_mfma_f32_16x16x32_bf16(a0, b0, acc, 0, 0, 0);
            acc = __builtin_amdgcn_mfma_f32_16x16x32_bf16(a1, b1, acc, 0, 0, 0);
            #pragma unroll
            for (int r = 0; r < 4; ++r)
                outv[r] += zdi[(w2 * 16 + lk * 4 + r) * 6 + k] * acc[r];
        }
        #pragma unroll
        for (int r = 0; r < 4; ++r) {
            int n = n0 + w2 * 16 + lk * 4 + r;
            if (n < NN) zouth[(size_t)n * NHD + h * DD + dt * 16 + lrow] = f2bf(outv[r] * inv6);
        }
    }
}

// ---------------------------------------------------------------- K7: output projection (bf16 in, f32 out)
__global__ __launch_bounds__(256) void outproj_kernel(
    const unsigned short* __restrict__ zouth, const float* __restrict__ Wo,
    const float* __restrict__ bo, float* __restrict__ out) {
    __shared__ float zsh[16][NHD];
    const int t = threadIdx.x;
    const int n0 = blockIdx.x * 16;
    const uint4* zg = (const uint4*)zouth;
    #pragma unroll
    for (int q = 0; q < 2; ++q) {
        int idx = t + q * 256;
        int row = idx >> 5, g = idx & 31;
        uint4 v = zg[(size_t)(n0 + row) * 32 + g];
        const unsigned short* e = (const unsigned short*)&v;
        #pragma unroll
        for (int j = 0; j < 8; ++j) zsh[row][g * 8 + j] = bf2f(e[j]);
    }
    __syncthreads();
    const int c = t & 63, g = t >> 6;
    float acc[4];
    #pragma unroll
    for (int i = 0; i < 4; ++i) acc[i] = bo[c];
    for (int r = 0; r < 256; ++r) {
        float w = Wo[r * 64 + c];
        #pragma unroll
        for (int i = 0; i < 4; ++i) acc[i] += zsh[g + 4 * i][r] * w;
    }
    #pragma unroll
    for (int i = 0; i < 4; ++i)
        out[(n0 + g + 4 * i) * 64 + c] = acc[i];
}

// ---------------------------------------------------------------- K8: edges, fp8 gather + HW decode
__global__ __launch_bounds__(256) void edge_fp8_kernel(
    const unsigned char* __restrict__ qb8, const unsigned char* __restrict__ kb8,
    const int* __restrict__ ei, const float* __restrict__ nrm,
    float* __restrict__ out) {
    const int t = threadIdx.x;
    const int li = t & 15;
    const int e = blockIdx.x * 16 + (t >> 4);
    const int s = ei[e], d = ei[EE + e];
    uint4 qv = ((const uint4*)qb8)[d * 16 + li];
    uint4 kv = ((const uint4*)kb8)[s * 16 + li];
    float qf[16], kf[16];
    fp8x4tof(qv.x, qf + 0);  fp8x4tof(qv.y, qf + 4);
    fp8x4tof(qv.z, qf + 8);  fp8x4tof(qv.w, qf + 12);
    fp8x4tof(kv.x, kf + 0);  fp8x4tof(kv.y, kf + 4);
    fp8x4tof(kv.z, kf + 8);  fp8x4tof(kv.w, kf + 12);
    float p = 0.f;
    #pragma unroll
    for (int i = 0; i < 16; ++i) p = fmaf(qf[i], kf[i], p);
    p += __shfl_xor(p, 1, 64);
    p += __shfl_xor(p, 2, 64);
    if ((li & 3) == 0) {
        int h = li >> 2;
        out[ZOFF + e * 4 + h] = p * (1.0f / (2048.f * 2048.f)) / nrm[d * HH + h];
    }
}

// ---------------------------------------------------------------- launch
extern "C" void kernel_launch(void* const* d_in, const int* in_sizes, int n_in,
                              void* d_out, int out_size, void* d_ws, size_t ws_size,
                              hipStream_t stream) {
    (void)in_sizes; (void)n_in; (void)out_size;
    const float* z  = (const float*)d_in[0];
    const float* Wq = (const float*)d_in[1];
    const float* bq = (const float*)d_in[2];
    const float* Wk = (const float*)d_in[3];
    const float* bk = (const float*)d_in[4];
    const float* Wv = (const float*)d_in[5];
    const float* bv = (const float*)d_in[6];
    const float* Wo = (const float*)d_in[7];
    const float* bo = (const float*)d_in[8];
    const float* proj = (const float*)d_in[9];
    const float* gum  = (const float*)d_in[10];
    const int*   ei   = (const int*)d_in[11];
    float* out = (float*)d_out;
    float* ws = (float*)d_ws;

    if (ws_size / 4 < (size_t)38673348) return;

    // region map (floats):
    // [0, 1.92M)       : zh (pre-qkv) -> qb8 (feat onward, read by edge)
    // [1.92M, 3.84M)   : zh tail -> kb8 (kfin_tr onward, read by edge)
    // [3.84M, 4.0M)    : WT (pre-qkv only)
    // [4.0M, 10.15M)   : kvsp bf16 (kvs->reduce; kb region [7.68M..] dead after kfin_tr)
    // [7.68M, 15.36M)  : kb f32 (feat -> kfin_tr, then dead)
    // [15.36M, 19.2M)  : vh bf16 (qkv->transp) -> ksp/ksump (kvs->reduce) -> zouth (znum->outproj)
    // [23.04M ...)     : kvshT, projh, kss, ksum, nrm, gmax, qbh, kbh, kbhT, vbhT
    float* kb    = ws + 7680000;
    unsigned short* zouth = (unsigned short*)(ws + 15360000);
    unsigned short* vh = (unsigned short*)(ws + 15360000);
    unsigned short* kvshT = (unsigned short*)(ws + 23040000);
    unsigned short* projh = (unsigned short*)(ws + 23089152);
    float* kss   = ws + 23138304;
    float* ksum  = ws + 23139840;
    float* nrm   = ws + 23140096;
    unsigned* gmax = (unsigned*)(ws + 23260096);
    unsigned short* qbh = (unsigned short*)(ws + 23260100);
    unsigned short* kbh = (unsigned short*)(ws + 27100100);
    unsigned short* kbhT = (unsigned short*)(ws + 30940100);
    unsigned short* vbhT = (unsigned short*)(ws + 34806724);
    unsigned short* zh = (unsigned short*)ws;                  // dead after qkv
    unsigned short* WT = (unsigned short*)(ws + 3840000);      // dead after qkv
    unsigned char* qb8 = (unsigned char*)ws;                   // 7.68M bytes
    unsigned char* kb8 = (unsigned char*)(ws + 1920000);       // 7.68M bytes
    unsigned short* kvsp = (unsigned short*)(ws + 4000000);    // NCS*98304 bf16
    float* ksp   = ws + 16300000;                              // NCS*1536 (vh dead by kvs)
    float* ksump = ws + 16700000;                              // NCS*256

    init_kernel<<<1, 64, 0, stream>>>(gmax);
    zcast_kernel<<<3750, 256, 0, stream>>>(z, zh);
    wtransp_kernel<<<dim3(8, 3), 256, 0, stream>>>(Wq, Wk, Wv, WT);
    projcast_kernel<<<16, 256, 0, stream>>>(proj, projh);
    qkv_mfma_kernel<<<dim3(235, 3), 256, 0, stream>>>(zh, WT, bq, bk, bv, qbh, kbh, vh);
    transp_bf16_kernel<<<dim3(472, HH), 256, 0, stream>>>(vh, vbhT);
    feat_mfma_kernel<<<dim3(469, HH), 256, 0, stream>>>(qbh, kbh, kb, projh, gmax, qb8);
    kfin_tr_kernel<<<dim3(472, HH), 256, 0, stream>>>(kb, gmax, kbh, kbhT, kb8);
    kvs_kernel<<<dim3(NCS, HH), 512, 0, stream>>>(kbhT, vbhT, gum, kvsp, ksp, ksump);
    reduce_kernel<<<392, 256, 0, stream>>>(kvsp, ksp, ksump, kvshT, kss, ksum);
    znum_kernel<<<dim3(469, HH), 512, 0, stream>>>(qbh, kvshT, kss, ksum, zouth, nrm);
    outproj_kernel<<<1875, 256, 0, stream>>>(zouth, Wo, bo, out);
    edge_fp8_kernel<<<30000, 256, 0, stream>>>(qb8, kb8, ei, nrm, out);
}

// Round 21
// 204.092 us; speedup vs baseline: 1.0987x; 1.0133x over previous
//
#include <hip/hip_runtime.h>
#include <hip/hip_bf16.h>

#define NN   30000
#define DIN  128
#define NHD  256      // H*D
#define HH   4
#define DD   64
#define MM   64
#define KK   6
#define EE   480000
#define ZOFF 1920000  // 30000*64
#define NCS   125
#define CHUNK 240
#define PITCH  30208   // padded bf16 elems per row of kbhT/vbhT
#define PITCH4 3776    // uint4 per row

typedef __attribute__((ext_vector_type(8))) short bf16x8;
typedef __attribute__((ext_vector_type(4))) float f32x4;
typedef __attribute__((ext_vector_type(2))) float f32x2;

__device__ __forceinline__ unsigned f2key(float f) {
    unsigned u = __float_as_uint(f);
    return (u & 0x80000000u) ? ~u : (u | 0x80000000u);
}
__device__ __forceinline__ float key2f(unsigned k) {
    return __uint_as_float((k & 0x80000000u) ? (k ^ 0x80000000u) : ~k);
}
__device__ __forceinline__ unsigned short f2bf(float f) {   // RNE
    unsigned u = __float_as_uint(f);
    unsigned r = ((u >> 16) & 1u) + 0x7fffu;
    return (unsigned short)((u + r) >> 16);
}
__device__ __forceinline__ float bf2f(unsigned short u) {
    return __uint_as_float((unsigned)u << 16);
}
// fp8 e4m3fn, POSITIVE values only, RNE, satfinite (software fallback)
__device__ __forceinline__ unsigned char ftofp8(float x) {
    unsigned u = __float_as_uint(x);
    int e32 = (int)(u >> 23) - 127;
    if (e32 <= -7) {
        int m = (int)rintf(x * 512.f);
        return (unsigned char)m;
    }
    unsigned r = ((u >> 20) & 1u) + 0x7FFFFu;
    u += r;
    e32 = (int)(u >> 23) - 127;
    if (e32 > 8) return 0x7E;
    int m = (u >> 20) & 7;
    return (unsigned char)(((e32 + 7) << 3) | m);
}
__device__ __forceinline__ float fp8tof(unsigned char u) {
    int e = (u >> 3) & 15, m = u & 7;
    if (e == 0) return (float)m * 0.001953125f;
    return __uint_as_float((unsigned)((e + 120) << 23) | ((unsigned)m << 20));
}
// pack 4 f32 -> 4 fp8 bytes (HW converter when available)
__device__ __forceinline__ unsigned fp8pack4(float a, float b, float c, float d) {
#if __has_builtin(__builtin_amdgcn_cvt_pk_fp8_f32)
    int w = __builtin_amdgcn_cvt_pk_fp8_f32(a, b, 0, false);
    w = __builtin_amdgcn_cvt_pk_fp8_f32(c, d, w, true);
    return (unsigned)w;
#else
    return (unsigned)ftofp8(a) | ((unsigned)ftofp8(b) << 8) |
           ((unsigned)ftofp8(c) << 16) | ((unsigned)ftofp8(d) << 24);
#endif
}
// decode 4 fp8 bytes of a uint -> 4 floats (HW converter when available)
__device__ __forceinline__ void fp8x4tof(unsigned w, float* o) {
#if __has_builtin(__builtin_amdgcn_cvt_pk_f32_fp8)
    f32x2 lo = __builtin_amdgcn_cvt_pk_f32_fp8((int)w, false);
    f32x2 hi = __builtin_amdgcn_cvt_pk_f32_fp8((int)w, true);
    o[0] = lo[0]; o[1] = lo[1]; o[2] = hi[0]; o[3] = hi[1];
#else
    o[0] = fp8tof((unsigned char)(w & 255));
    o[1] = fp8tof((unsigned char)((w >> 8) & 255));
    o[2] = fp8tof((unsigned char)((w >> 16) & 255));
    o[3] = fp8tof((unsigned char)((w >> 24) & 255));
#endif
}
__device__ __forceinline__ unsigned short f2h(float x) {   // f32 -> f16 RNE
    _Float16 h = (_Float16)x;
    return *(unsigned short*)&h;
}
__device__ __forceinline__ float h2f(unsigned short u) {
    _Float16 h = *(_Float16*)&u;
    return (float)h;
}

// ---------------------------------------------------------------- init
__global__ void init_kernel(unsigned* gmax) {
    if (threadIdx.x < HH) gmax[threadIdx.x] = 0u;
}

// ---------------------------------------------------------------- K0a: z -> bf16
__global__ __launch_bounds__(256) void zcast_kernel(
    const float* __restrict__ z, unsigned short* __restrict__ zh) {
    int idx = blockIdx.x * 256 + threadIdx.x;   // 960,000 float4 exactly
    float4 v = ((const float4*)z)[idx];
    ushort4 u;
    u.x = f2bf(v.x); u.y = f2bf(v.y); u.z = f2bf(v.z); u.w = f2bf(v.w);
    ((ushort4*)zh)[idx] = u;
}

// ---------------------------------------------------------------- K0b: W [128][256] -> WT bf16 [256][128]
__global__ __launch_bounds__(256) void wtransp_kernel(
    const float* __restrict__ Wq, const float* __restrict__ Wk,
    const float* __restrict__ Wv, unsigned short* __restrict__ WT) {
    __shared__ unsigned short tl[64][72];
    const int t = threadIdx.x;
    const int kt = blockIdx.x & 1, ct = blockIdx.x >> 1;
    const int wi = blockIdx.y;
    const float* W = (wi == 0) ? Wq : (wi == 1) ? Wk : Wv;
    const float4* W4 = (const float4*)W;
    #pragma unroll
    for (int it = 0; it < 4; ++it) {
        int idx = t + it * 256;
        int r = idx >> 4, c4 = idx & 15;
        float4 v = W4[(kt * 64 + r) * 64 + ct * 16 + c4];
        tl[c4 * 4 + 0][r] = f2bf(v.x);
        tl[c4 * 4 + 1][r] = f2bf(v.y);
        tl[c4 * 4 + 2][r] = f2bf(v.z);
        tl[c4 * 4 + 3][r] = f2bf(v.w);
    }
    __syncthreads();
    uint4* d4 = (uint4*)WT;
    #pragma unroll
    for (int it = 0; it < 2; ++it) {
        int idx = t + it * 256;
        int m = idx >> 3, g = idx & 7;
        d4[((size_t)wi * 256 + ct * 64 + m) * 16 + kt * 8 + g] = *(uint4*)&tl[m][g * 8];
    }
}

// ---------------------------------------------------------------- K0c: proj*dn -> bf16
__global__ void projcast_kernel(const float* __restrict__ proj,
                                unsigned short* __restrict__ projh) {
    int i = blockIdx.x * 256 + threadIdx.x;   // 4096 exactly
    projh[i] = f2bf(proj[i] * 0.35355339059327373f);
}

// ---------------------------------------------------------------- K1: qkv via MFMA bf16, bf16 outputs
__global__ __launch_bounds__(256) void qkv_mfma_kernel(
    const unsigned short* __restrict__ zh, const unsigned short* __restrict__ WT,
    const float* __restrict__ bq, const float* __restrict__ bk, const float* __restrict__ bv,
    unsigned short* __restrict__ qh, unsigned short* __restrict__ kh,
    unsigned short* __restrict__ vh) {
    __shared__ __align__(16) unsigned short zt[128 * 128];
    __shared__ __align__(16) unsigned short wt[64 * 128];
    const int t = threadIdx.x;
    const int n0 = blockIdx.x * 128;
    const int wi = blockIdx.y;
    const float sc = (wi == 2) ? 1.0f : 2.0f;
    const float* bias = (wi == 0) ? bq : (wi == 1) ? bk : bv;
    unsigned short* outp = (wi == 0) ? qh : (wi == 1) ? kh : vh;
    const uint4* zg = (const uint4*)zh;
    #pragma unroll
    for (int it = 0; it < 8; ++it) {
        int idx = t + it * 256;
        int row = idx >> 4, g = idx & 15;
        int n = n0 + row;
        uint4 v = make_uint4(0u, 0u, 0u, 0u);
        if (n < NN) v = zg[(size_t)n * 16 + g];
        *(uint4*)&zt[row * 128 + ((g ^ (row & 7)) * 8)] = v;
    }
    const uint4* wg = (const uint4*)WT + (size_t)wi * 4096;
    const int w = t >> 6, lane = t & 63, lrow = lane & 15, lk = lane >> 4;
    for (int cc = 0; cc < 4; ++cc) {
        __syncthreads();
        #pragma unroll
        for (int it = 0; it < 4; ++it) {
            int idx = t + it * 256;
            int r = idx >> 4, g = idx & 15;
            *(uint4*)&wt[r * 128 + ((g ^ (r & 7)) * 8)] = wg[(cc * 64 + r) * 16 + g];
        }
        __syncthreads();
        f32x4 acc[4][2];
        #pragma unroll
        for (int mt = 0; mt < 4; ++mt) {
            acc[mt][0] = (f32x4){0.f, 0.f, 0.f, 0.f};
            acc[mt][1] = (f32x4){0.f, 0.f, 0.f, 0.f};
        }
        #pragma unroll
        for (int ks = 0; ks < 4; ++ks) {
            const int g0 = ks * 4 + lk;
            bf16x8 a[4], b[2];
            #pragma unroll
            for (int mt = 0; mt < 4; ++mt) {
                int r = mt * 16 + lrow;
                a[mt] = *(const bf16x8*)&wt[r * 128 + ((g0 ^ (r & 7)) * 8)];
            }
            #pragma unroll
            for (int nt = 0; nt < 2; ++nt) {
                int node = (w * 2 + nt) * 16 + lrow;
                b[nt] = *(const bf16x8*)&zt[node * 128 + ((g0 ^ (node & 7)) * 8)];
            }
            #pragma unroll
            for (int mt = 0; mt < 4; ++mt)
                #pragma unroll
                for (int nt = 0; nt < 2; ++nt)
                    acc[mt][nt] = __builtin_amdgcn_mfma_f32_16x16x32_bf16(
                        a[mt], b[nt], acc[mt][nt], 0, 0, 0);
        }
        #pragma unroll
        for (int mt = 0; mt < 4; ++mt) {
            int cbase = cc * 64 + mt * 16 + lk * 4;
            float4 bi = *(const float4*)&bias[cbase];
            #pragma unroll
            for (int nt = 0; nt < 2; ++nt) {
                int n = n0 + (w * 2 + nt) * 16 + lrow;
                if (n < NN) {
                    ushort4 u;
                    u.x = f2bf((acc[mt][nt][0] + bi.x) * sc);
                    u.y = f2bf((acc[mt][nt][1] + bi.y) * sc);
                    u.z = f2bf((acc[mt][nt][2] + bi.z) * sc);
                    u.w = f2bf((acc[mt][nt][3] + bi.w) * sc);
                    *(ushort4*)&outp[(size_t)n * NHD + cbase] = u;
                }
            }
        }
    }
}

// ---------------------------------------------------------------- K2: random features via MFMA (+ fused fp8 qp, f16 kb)
__global__ __launch_bounds__(256) void feat_mfma_kernel(
    unsigned short* __restrict__ qbh, const unsigned short* __restrict__ kh,
    unsigned short* __restrict__ kbf, const unsigned short* __restrict__ projh,
    unsigned* __restrict__ gmax, unsigned char* __restrict__ qb8) {
    __shared__ __align__(16) unsigned short at[64 * 64];
    __shared__ __align__(16) unsigned short pb[64 * 64];
    __shared__ __align__(16) float ddt[64 * 68];
    __shared__ float diag_sh[64];
    __shared__ float wmax_sh[4];
    const int t = threadIdx.x;
    const int h = blockIdx.y;
    const int n0 = blockIdx.x * 64;
    const int tx = t & 15, ty = t >> 4;
    const uint4* pg = (const uint4*)projh;
    #pragma unroll
    for (int q = 0; q < 2; ++q) {
        int idx = t + q * 256;
        int m = idx >> 3, g = idx & 7;
        *(uint4*)&pb[m * 64 + ((g ^ (m & 7)) * 8)] = pg[idx];
    }
    const int w = t >> 6, lane = t & 63, lrow = lane & 15, lk = lane >> 4;
    const int arow = w * 16 + lrow;
    #pragma unroll
    for (int pass = 0; pass < 2; ++pass) {
        const uint4* src = (const uint4*)(pass ? kh : qbh);
        __syncthreads();
        #pragma unroll
        for (int q = 0; q < 2; ++q) {
            int idx = t + q * 256;
            int n = idx >> 3, g = idx & 7;
            uint4 v = make_uint4(0u, 0u, 0u, 0u);
            if (n0 + n < NN) v = src[(size_t)(n0 + n) * 32 + h * 8 + g];
            *(uint4*)&at[n * 64 + ((g ^ (n & 7)) * 8)] = v;
            const unsigned short* e8 = (const unsigned short*)&v;
            float ss = 0.f;
            #pragma unroll
            for (int j2 = 0; j2 < 8; ++j2) { float f = bf2f(e8[j2]); ss += f * f; }
            ss += __shfl_xor(ss, 1, 64);
            ss += __shfl_xor(ss, 2, 64);
            ss += __shfl_xor(ss, 4, 64);
            if (g == 0) diag_sh[n] = 0.0625f * ss;   // 0.5 * dn^2 * sum
        }
        __syncthreads();
        bf16x8 a0 = *(const bf16x8*)&at[arow * 64 + ((lk ^ (arow & 7)) * 8)];
        bf16x8 a1 = *(const bf16x8*)&at[arow * 64 + (((lk + 4) ^ (arow & 7)) * 8)];
        #pragma unroll
        for (int ct = 0; ct < 4; ++ct) {
            int brow = ct * 16 + lrow;
            bf16x8 b0 = *(const bf16x8*)&pb[brow * 64 + ((lk ^ (brow & 7)) * 8)];
            bf16x8 b1 = *(const bf16x8*)&pb[brow * 64 + (((lk + 4) ^ (brow & 7)) * 8)];
            f32x4 acc = {0.f, 0.f, 0.f, 0.f};
            acc = __builtin_amdgcn_mfma_f32_16x16x32_bf16(a0, b0, acc, 0, 0, 0);
            acc = __builtin_amdgcn_mfma_f32_16x16x32_bf16(a1, b1, acc, 0, 0, 0);
            #pragma unroll
            for (int r = 0; r < 4; ++r)
                ddt[(w * 16 + lk * 4 + r) * 68 + ct * 16 + lrow] = acc[r];
        }
        __syncthreads();
        if (pass == 0) {
            #pragma unroll
            for (int i = 0; i < 4; ++i) {
                int n = n0 + ty * 4 + i;
                float a_[4];
                #pragma unroll
                for (int j = 0; j < 4; ++j) a_[j] = ddt[(ty * 4 + i) * 68 + tx * 4 + j];
                float mx = fmaxf(fmaxf(a_[0], a_[1]), fmaxf(a_[2], a_[3]));
                mx = fmaxf(mx, __shfl_xor(mx, 1, 64));
                mx = fmaxf(mx, __shfl_xor(mx, 2, 64));
                mx = fmaxf(mx, __shfl_xor(mx, 4, 64));
                mx = fmaxf(mx, __shfl_xor(mx, 8, 64));
                if (n < NN) {
                    float dg = diag_sh[ty * 4 + i] + mx;
                    float f0 = 0.125f * (__expf(a_[0] - dg) + 1e-6f);
                    float f1 = 0.125f * (__expf(a_[1] - dg) + 1e-6f);
                    float f2 = 0.125f * (__expf(a_[2] - dg) + 1e-6f);
                    float f3 = 0.125f * (__expf(a_[3] - dg) + 1e-6f);
                    ushort4 u;
                    u.x = f2bf(f0); u.y = f2bf(f1); u.z = f2bf(f2); u.w = f2bf(f3);
                    *(ushort4*)&qbh[(size_t)n * NHD + h * DD + tx * 4] = u;
                    unsigned pk = fp8pack4(bf2f(u.x) * 2048.f, bf2f(u.y) * 2048.f,
                                           bf2f(u.z) * 2048.f, bf2f(u.w) * 2048.f);
                    *(unsigned*)&qb8[(size_t)n * NHD + h * DD + tx * 4] = pk;
                }
            }
        } else {
            float km = -3.4e38f;
            #pragma unroll
            for (int i = 0; i < 4; ++i) {
                int n = n0 + ty * 4 + i;
                if (n < NN) {
                    float a_[4];
                    #pragma unroll
                    for (int j = 0; j < 4; ++j) a_[j] = ddt[(ty * 4 + i) * 68 + tx * 4 + j];
                    float dg = diag_sh[ty * 4 + i];
                    ushort4 o;
                    o.x = f2h(a_[0] - dg); o.y = f2h(a_[1] - dg);
                    o.z = f2h(a_[2] - dg); o.w = f2h(a_[3] - dg);
                    *(ushort4*)&kbf[(size_t)n * NHD + h * DD + tx * 4] = o;
                    km = fmaxf(km, fmaxf(fmaxf(a_[0], a_[1]), fmaxf(a_[2], a_[3])));
                }
            }
            #pragma unroll
            for (int off = 1; off < 64; off <<= 1) km = fmaxf(km, __shfl_xor(km, off, 64));
            if ((t & 63) == 0) wmax_sh[t >> 6] = km;
            __syncthreads();
            if (t == 0) {
                float m2 = fmaxf(fmaxf(wmax_sh[0], wmax_sh[1]), fmaxf(wmax_sh[2], wmax_sh[3]));
                atomicMax(&gmax[h], f2key(m2));
            }
        }
    }
}

// ---------------------------------------------------------------- K3: fused kp finalize + transpose + fp8 (f16 in)
__global__ __launch_bounds__(256) void kfin_tr_kernel(
    const unsigned short* __restrict__ kbf, const unsigned* __restrict__ gmax,
    unsigned short* __restrict__ kbh, unsigned short* __restrict__ kbhT,
    unsigned char* __restrict__ kb8) {
    __shared__ unsigned short tl[64][72];
    const int t = threadIdx.x;
    const int n0 = blockIdx.x * 64;
    const int h = blockIdx.y;
    const float mx = key2f(gmax[h]);
    const ushort4* s4 = (const ushort4*)kbf;
    #pragma unroll
    for (int it = 0; it < 4; ++it) {
        int idx = t + it * 256;
        int n = idx >> 4, c4 = idx & 15;
        ushort4 u = make_ushort4(0, 0, 0, 0);
        if (n0 + n < NN) {
            ushort4 v = s4[(size_t)(n0 + n) * 64 + h * 16 + c4];
            float f0 = 0.125f * (__expf(h2f(v.x) - mx) + 1e-6f);
            float f1 = 0.125f * (__expf(h2f(v.y) - mx) + 1e-6f);
            float f2 = 0.125f * (__expf(h2f(v.z) - mx) + 1e-6f);
            float f3 = 0.125f * (__expf(h2f(v.w) - mx) + 1e-6f);
            u.x = f2bf(f0); u.y = f2bf(f1); u.z = f2bf(f2); u.w = f2bf(f3);
            *(ushort4*)&kbh[(size_t)(n0 + n) * NHD + h * DD + c4 * 4] = u;
            unsigned pk = fp8pack4(bf2f(u.x) * 2048.f, bf2f(u.y) * 2048.f,
                                   bf2f(u.z) * 2048.f, bf2f(u.w) * 2048.f);
            *(unsigned*)&kb8[(size_t)(n0 + n) * NHD + h * DD + c4 * 4] = pk;
        }
        tl[c4 * 4 + 0][n] = u.x;
        tl[c4 * 4 + 1][n] = u.y;
        tl[c4 * 4 + 2][n] = u.z;
        tl[c4 * 4 + 3][n] = u.w;
    }
    __syncthreads();
    uint4* d4 = (uint4*)kbhT;
    #pragma unroll
    for (int it = 0; it < 2; ++it) {
        int idx = t + it * 256;
        int m = idx >> 3, g = idx & 7;
        d4[(size_t)(h * 64 + m) * PITCH4 + (n0 >> 3) + g] = *(uint4*)&tl[m][g * 8];
    }
}

// ---------------------------------------------------------------- K3b: transpose bf16 [n][256] -> [h*64+c][n]
__global__ __launch_bounds__(256) void transp_bf16_kernel(
    const unsigned short* __restrict__ src, unsigned short* __restrict__ dst) {
    __shared__ unsigned short tl[64][72];
    const int t = threadIdx.x;
    const int nt = blockIdx.x * 64;
    const int h = blockIdx.y;
    const uint4* s4 = (const uint4*)src;
    #pragma unroll
    for (int it = 0; it < 2; ++it) {
        int idx = t + it * 256;
        int n = idx >> 3, g = idx & 7;
        uint4 v = make_uint4(0u, 0u, 0u, 0u);
        if (nt + n < NN) v = s4[(size_t)(nt + n) * 32 + h * 8 + g];
        const unsigned short* e = (const unsigned short*)&v;
        #pragma unroll
        for (int j = 0; j < 8; ++j) tl[g * 8 + j][n] = e[j];
    }
    __syncthreads();
    uint4* d4 = (uint4*)dst;
    #pragma unroll
    for (int it = 0; it < 2; ++it) {
        int idx = t + it * 256;
        int m = idx >> 3, g = idx & 7;
        d4[(size_t)(h * 64 + m) * PITCH4 + (nt >> 3) + g] = *(uint4*)&tl[m][g * 8];
    }
}

// ---------------------------------------------------------------- K4: kvs via MFMA bf16 (hoisted kpw, NCS grid)
__global__ __launch_bounds__(512) void kvs_kernel(
    const unsigned short* __restrict__ kbhT, const unsigned short* __restrict__ vbhT,
    const float* __restrict__ gum,
    unsigned short* __restrict__ kvsp, float* __restrict__ ksp, float* __restrict__ ksump) {
    __shared__ __align__(16) unsigned short va [64 * 64];
    __shared__ __align__(16) unsigned short kpw[KK][64 * 64];
    __shared__ float w_sh[KK][256];
    const int c = blockIdx.x, h = blockIdx.y;
    const int t = threadIdx.x;
    const int n0 = c * CHUNK;
    const int n1 = n0 + CHUNK;
    for (int i = t; i < 256; i += 512) {
        int n = n0 + i;
        bool ok = (i < CHUNK);
        #pragma unroll
        for (int k = 0; k < KK; ++k)
            w_sh[k][i] = ok ? __expf(gum[n * 24 + h * KK + k] * 4.0f) : 0.f;
    }
    const int m_ = t >> 3, g_ = t & 7;
    const int w = t >> 6, lane = t & 63, lrow = lane & 15, lk = lane >> 4;
    const int ds = w & 3, mh = w >> 2;
    const int arow = ds * 16 + lrow;
    f32x4 acc[KK][2];
    #pragma unroll
    for (int k = 0; k < KK; ++k) {
        acc[k][0] = (f32x4){0.f, 0.f, 0.f, 0.f};
        acc[k][1] = (f32x4){0.f, 0.f, 0.f, 0.f};
    }
    float ks_acc[KK] = {0.f, 0.f, 0.f, 0.f, 0.f, 0.f};
    float ksum_acc = 0.f;
    const uint4* kT4 = (const uint4*)kbhT;
    const uint4* vT4 = (const uint4*)vbhT;
    __syncthreads();   // w_sh ready
    #pragma unroll
    for (int s = 0; s < 4; ++s) {
        const int nb = n0 + s * 64;
        uint4 kvv = kT4[(size_t)(h * 64 + m_) * PITCH4 + (nb >> 3) + g_];
        uint4 vvv = vT4[(size_t)(h * 64 + m_) * PITCH4 + (nb >> 3) + g_];
        const int slot = g_ ^ (m_ & 7);
        *(uint4*)&va[m_ * 64 + slot * 8] = vvv;
        float kf[8];
        {
            const unsigned short* ke = (const unsigned short*)&kvv;
            float sl = 0.f;
            int nbase = nb + g_ * 8;
            #pragma unroll
            for (int e = 0; e < 8; ++e) {
                kf[e] = bf2f(ke[e]);
                if (nbase + e < n1) sl += kf[e];
            }
            sl += __shfl_xor(sl, 1, 64);
            sl += __shfl_xor(sl, 2, 64);
            sl += __shfl_xor(sl, 4, 64);
            if (g_ == 0) ksum_acc += sl;
        }
        const int bw = s * 64;
        const int gg = g_ ^ (m_ & 7);
        #pragma unroll
        for (int k = 0; k < KK; ++k) {
            unsigned short ov[8];
            float sl = 0.f;
            #pragma unroll
            for (int e = 0; e < 8; ++e) {
                float p = kf[e] * w_sh[k][bw + gg * 8 + e];
                sl += p;
                ov[e] = f2bf(p);
            }
            *(uint4*)&kpw[k][m_ * 64 + g_ * 8] = *(uint4*)ov;
            sl += __shfl_xor(sl, 1, 64);
            sl += __shfl_xor(sl, 2, 64);
            sl += __shfl_xor(sl, 4, 64);
            if (g_ == 0) ks_acc[k] += sl;
        }
        __syncthreads();
        bf16x8 a0 = *(const bf16x8*)&va[arow * 64 + ((lk ^ (arow & 7)) * 8)];
        bf16x8 a1 = *(const bf16x8*)&va[arow * 64 + (((lk + 4) ^ (arow & 7)) * 8)];
        #pragma unroll
        for (int k = 0; k < KK; ++k) {
            #pragma unroll
            for (int mt = 0; mt < 2; ++mt) {
                int m = (mh * 2 + mt) * 16 + lrow;
                bf16x8 b0 = *(const bf16x8*)&kpw[k][m * 64 + ((lk ^ (m & 7)) * 8)];
                bf16x8 b1 = *(const bf16x8*)&kpw[k][m * 64 + (((lk + 4) ^ (m & 7)) * 8)];
                acc[k][mt] = __builtin_amdgcn_mfma_f32_16x16x32_bf16(a0, b0, acc[k][mt], 0, 0, 0);
                acc[k][mt] = __builtin_amdgcn_mfma_f32_16x16x32_bf16(a1, b1, acc[k][mt], 0, 0, 0);
            }
        }
        __syncthreads();
    }
    const size_t cb = (size_t)(c * HH + h) * KK;
    #pragma unroll
    for (int k = 0; k < KK; ++k)
        #pragma unroll
        for (int mt = 0; mt < 2; ++mt) {
            int m = (mh * 2 + mt) * 16 + lrow;
            #pragma unroll
            for (int r = 0; r < 4; ++r) {
                int d = ds * 16 + lk * 4 + r;
                kvsp[(cb + k) * 4096 + d * 64 + m] = f2bf(acc[k][mt][r]);
            }
        }
    if (g_ == 0) {
        #pragma unroll
        for (int k = 0; k < KK; ++k)
            ksp[(cb + k) * 64 + m_] = ks_acc[k];
        ksump[(size_t)(c * HH + h) * 64 + m_] = ksum_acc;
    }
}

// ---------------------------------------------------------------- K5: reduce bf16 partials
__global__ void reduce_kernel(const unsigned short* __restrict__ kvsp,
                              const float* __restrict__ ksp, const float* __restrict__ ksump,
                              unsigned short* __restrict__ kvshT, float* __restrict__ kss,
                              float* __restrict__ ksum) {
    int idx = blockIdx.x * 256 + threadIdx.x;
    if (idx < 98304) {
        float s = 0.f;
        for (int c = 0; c < NCS; ++c) s += bf2f(kvsp[c * 98304 + idx]);
        kvshT[idx] = f2bf(s);
    } else if (idx < 98304 + 1536) {
        int o = idx - 98304;
        float s = 0.f;
        for (int c = 0; c < NCS; ++c) s += ksp[c * 1536 + o];
        kss[o] = s;
    } else if (idx < 98304 + 1536 + 256) {
        int o = idx - 98304 - 1536;
        float s = 0.f;
        for (int c = 0; c < NCS; ++c) s += ksump[c * 256 + o];
        ksum[o] = s;
    }
}

// ---------------------------------------------------------------- K6: znum via MFMA bf16 (512 thr, MFMA z_den)
__global__ __launch_bounds__(512) void znum_kernel(
    const unsigned short* __restrict__ qbh, const unsigned short* __restrict__ kvshT,
    const float* __restrict__ kss, const float* __restrict__ ksum,
    unsigned short* __restrict__ zouth, float* __restrict__ nrm) {
    __shared__ __align__(16) unsigned short qpa[64 * 64];
    __shared__ __align__(16) unsigned short bt[6 * 64 * 64];
    __shared__ __align__(16) unsigned short bbuf[16 * 72];
    __shared__ float zdi[64 * 6];
    const int t = threadIdx.x;
    const int h = blockIdx.y;
    const int n0 = blockIdx.x * 64;
    const uint4* qg = (const uint4*)qbh;
    {
        int row = t >> 3, c8 = t & 7;
        int n = n0 + row;
        uint4 v = make_uint4(0u, 0u, 0u, 0u);
        if (n < NN) v = qg[n * 32 + h * 8 + c8];
        *(uint4*)&qpa[row * 64 + ((c8 ^ (row & 7)) * 8)] = v;
    }
    const uint4* bg = (const uint4*)kvshT;
    #pragma unroll
    for (int q = 0; q < 6; ++q) {
        int idx = t + q * 512;
        int kd = idx >> 3, c8 = idx & 7;
        *(uint4*)&bt[kd * 64 + ((c8 ^ (kd & 7)) * 8)] = bg[h * 3072 + idx];
    }
    #pragma unroll
    for (int q = 0; q < 2; ++q) {
        int idx = t + q * 512;
        int col = idx >> 6, m = idx & 63;
        float v = 0.f;
        if (col < 6) v = kss[h * 384 + col * 64 + m];
        else if (col == 6) v = ksum[h * 64 + m];
        bbuf[col * 72 + m] = f2bf(v);
    }
    __syncthreads();
    const int w = t >> 6, lane = t & 63;
    const int lrow = lane & 15, lk = lane >> 4;
    const int w2 = w & 3, wh = w >> 2;
    const int arow = w2 * 16 + lrow;
    const int aswz = (arow & 7) << 3;
    bf16x8 a0 = *(const bf16x8*)&qpa[arow * 64 + ((lk * 8) ^ aswz)];
    bf16x8 a1 = *(const bf16x8*)&qpa[arow * 64 + ((lk * 8 + 32) ^ aswz)];
    if (wh == 0) {
        bf16x8 b0 = *(const bf16x8*)&bbuf[lrow * 72 + lk * 8];
        bf16x8 b1 = *(const bf16x8*)&bbuf[lrow * 72 + lk * 8 + 32];
        f32x4 acc = {0.f, 0.f, 0.f, 0.f};
        acc = __builtin_amdgcn_mfma_f32_16x16x32_bf16(a0, b0, acc, 0, 0, 0);
        acc = __builtin_amdgcn_mfma_f32_16x16x32_bf16(a1, b1, acc, 0, 0, 0);
        #pragma unroll
        for (int r = 0; r < 4; ++r) {
            int node = w2 * 16 + lk * 4 + r;
            if (lrow < 6) zdi[node * 6 + lrow] = 1.0f / acc[r];
            else if (lrow == 6) {
                int n = n0 + node;
                if (n < NN) nrm[n * HH + h] = acc[r];
            }
        }
    }
    __syncthreads();
    const float inv6 = 1.0f / 6.0f;
    #pragma unroll
    for (int dtt = 0; dtt < 2; ++dtt) {
        const int dt = wh * 2 + dtt;
        f32x4 outv = {0.f, 0.f, 0.f, 0.f};
        #pragma unroll
        for (int k = 0; k < KK; ++k) {
            int kd = k * 64 + dt * 16 + lrow;
            int sw = (kd & 7) << 3;
            bf16x8 b0 = *(const bf16x8*)&bt[kd * 64 + ((lk * 8) ^ sw)];
            bf16x8 b1 = *(const bf16x8*)&bt[kd * 64 + ((lk * 8 + 32) ^ sw)];
            f32x4 acc = {0.f, 0.f, 0.f, 0.f};
            acc = __builtin_amdgcn_mfma_f32_16x16x32_bf16(a0, b0, acc, 0, 0, 0);
            acc = __builtin_amdgcn_mfma_f32_16x16x32_bf16(a1, b1, acc, 0, 0, 0);
            #pragma unroll
            for (int r = 0; r < 4; ++r)
                outv[r] += zdi[(w2 * 16 + lk * 4 + r) * 6 + k] * acc[r];
        }
        #pragma unroll
        for (int r = 0; r < 4; ++r) {
            int n = n0 + w2 * 16 + lk * 4 + r;
            if (n < NN) zouth[(size_t)n * NHD + h * DD + dt * 16 + lrow] = f2bf(outv[r] * inv6);
        }
    }
}

// ---------------------------------------------------------------- K7: output projection (bf16 in, f32 out)
__global__ __launch_bounds__(256) void outproj_kernel(
    const unsigned short* __restrict__ zouth, const float* __restrict__ Wo,
    const float* __restrict__ bo, float* __restrict__ out) {
    __shared__ float zsh[16][NHD];
    const int t = threadIdx.x;
    const int n0 = blockIdx.x * 16;
    const uint4* zg = (const uint4*)zouth;
    #pragma unroll
    for (int q = 0; q < 2; ++q) {
        int idx = t + q * 256;
        int row = idx >> 5, g = idx & 31;
        uint4 v = zg[(size_t)(n0 + row) * 32 + g];
        const unsigned short* e = (const unsigned short*)&v;
        #pragma unroll
        for (int j = 0; j < 8; ++j) zsh[row][g * 8 + j] = bf2f(e[j]);
    }
    __syncthreads();
    const int c = t & 63, g = t >> 6;
    float acc[4];
    #pragma unroll
    for (int i = 0; i < 4; ++i) acc[i] = bo[c];
    for (int r = 0; r < 256; ++r) {
        float w = Wo[r * 64 + c];
        #pragma unroll
        for (int i = 0; i < 4; ++i) acc[i] += zsh[g + 4 * i][r] * w;
    }
    #pragma unroll
    for (int i = 0; i < 4; ++i)
        out[(n0 + g + 4 * i) * 64 + c] = acc[i];
}

// ---------------------------------------------------------------- K8: edges, fp8 gather + HW decode
__global__ __launch_bounds__(256) void edge_fp8_kernel(
    const unsigned char* __restrict__ qb8, const unsigned char* __restrict__ kb8,
    const int* __restrict__ ei, const float* __restrict__ nrm,
    float* __restrict__ out) {
    const int t = threadIdx.x;
    const int li = t & 15;
    const int e = blockIdx.x * 16 + (t >> 4);
    const int s = ei[e], d = ei[EE + e];
    uint4 qv = ((const uint4*)qb8)[d * 16 + li];
    uint4 kv = ((const uint4*)kb8)[s * 16 + li];
    float qf[16], kf[16];
    fp8x4tof(qv.x, qf + 0);  fp8x4tof(qv.y, qf + 4);
    fp8x4tof(qv.z, qf + 8);  fp8x4tof(qv.w, qf + 12);
    fp8x4tof(kv.x, kf + 0);  fp8x4tof(kv.y, kf + 4);
    fp8x4tof(kv.z, kf + 8);  fp8x4tof(kv.w, kf + 12);
    float p = 0.f;
    #pragma unroll
    for (int i = 0; i < 16; ++i) p = fmaf(qf[i], kf[i], p);
    p += __shfl_xor(p, 1, 64);
    p += __shfl_xor(p, 2, 64);
    if ((li & 3) == 0) {
        int h = li >> 2;
        out[ZOFF + e * 4 + h] = p * (1.0f / (2048.f * 2048.f)) / nrm[d * HH + h];
    }
}

// ---------------------------------------------------------------- launch
extern "C" void kernel_launch(void* const* d_in, const int* in_sizes, int n_in,
                              void* d_out, int out_size, void* d_ws, size_t ws_size,
                              hipStream_t stream) {
    (void)in_sizes; (void)n_in; (void)out_size;
    const float* z  = (const float*)d_in[0];
    const float* Wq = (const float*)d_in[1];
    const float* bq = (const float*)d_in[2];
    const float* Wk = (const float*)d_in[3];
    const float* bk = (const float*)d_in[4];
    const float* Wv = (const float*)d_in[5];
    const float* bv = (const float*)d_in[6];
    const float* Wo = (const float*)d_in[7];
    const float* bo = (const float*)d_in[8];
    const float* proj = (const float*)d_in[9];
    const float* gum  = (const float*)d_in[10];
    const int*   ei   = (const int*)d_in[11];
    float* out = (float*)d_out;
    float* ws = (float*)d_ws;

    if (ws_size / 4 < (size_t)38673348) return;

    // region map (floats):
    // [0, 1.92M)       : zh (pre-qkv) -> qb8 (feat onward, read by edge)
    // [1.92M, 3.84M)   : zh tail -> kb8 (kfin_tr onward, read by edge)
    // [3.84M, 4.0M)    : WT (pre-qkv only)
    // [4.0M, 10.15M)   : kvsp bf16 (kvs->reduce; kb region dead after kfin_tr)
    // [7.68M, 11.52M)  : kbf f16 (feat -> kfin_tr, then dead)  [inside kvsp span, sequenced]
    // [15.36M, 19.2M)  : vh bf16 (qkv->transp) -> ksp/ksump (kvs->reduce) -> zouth (znum->outproj)
    // [23.04M ...)     : kvshT, projh, kss, ksum, nrm, gmax, qbh, kbh, kbhT, vbhT
    unsigned short* kbf = (unsigned short*)(ws + 7680000);     // 7.68M f16 elems
    unsigned short* zouth = (unsigned short*)(ws + 15360000);
    unsigned short* vh = (unsigned short*)(ws + 15360000);
    unsigned short* kvshT = (unsigned short*)(ws + 23040000);
    unsigned short* projh = (unsigned short*)(ws + 23089152);
    float* kss   = ws + 23138304;
    float* ksum  = ws + 23139840;
    float* nrm   = ws + 23140096;
    unsigned* gmax = (unsigned*)(ws + 23260096);
    unsigned short* qbh = (unsigned short*)(ws + 23260100);
    unsigned short* kbh = (unsigned short*)(ws + 27100100);
    unsigned short* kbhT = (unsigned short*)(ws + 30940100);
    unsigned short* vbhT = (unsigned short*)(ws + 34806724);
    unsigned short* zh = (unsigned short*)ws;                  // dead after qkv
    unsigned short* WT = (unsigned short*)(ws + 3840000);      // dead after qkv
    unsigned char* qb8 = (unsigned char*)ws;                   // 7.68M bytes
    unsigned char* kb8 = (unsigned char*)(ws + 1920000);       // 7.68M bytes
    unsigned short* kvsp = (unsigned short*)(ws + 4000000);    // NCS*98304 bf16 (kbf dead by kvs)
    float* ksp   = ws + 16300000;                              // NCS*1536 (vh dead by kvs)
    float* ksump = ws + 16700000;                              // NCS*256

    init_kernel<<<1, 64, 0, stream>>>(gmax);
    zcast_kernel<<<3750, 256, 0, stream>>>(z, zh);
    wtransp_kernel<<<dim3(8, 3), 256, 0, stream>>>(Wq, Wk, Wv, WT);
    projcast_kernel<<<16, 256, 0, stream>>>(proj, projh);
    qkv_mfma_kernel<<<dim3(235, 3), 256, 0, stream>>>(zh, WT, bq, bk, bv, qbh, kbh, vh);
    transp_bf16_kernel<<<dim3(472, HH), 256, 0, stream>>>(vh, vbhT);
    feat_mfma_kernel<<<dim3(469, HH), 256, 0, stream>>>(qbh, kbh, kbf, projh, gmax, qb8);
    kfin_tr_kernel<<<dim3(472, HH), 256, 0, stream>>>(kbf, gmax, kbh, kbhT, kb8);
    kvs_kernel<<<dim3(NCS, HH), 512, 0, stream>>>(kbhT, vbhT, gum, kvsp, ksp, ksump);
    reduce_kernel<<<392, 256, 0, stream>>>(kvsp, ksp, ksump, kvshT, kss, ksum);
    znum_kernel<<<dim3(469, HH), 512, 0, stream>>>(qbh, kvshT, kss, ksum, zouth, nrm);
    outproj_kernel<<<1875, 256, 0, stream>>>(zouth, Wo, bo, out);
    edge_fp8_kernel<<<30000, 256, 0, stream>>>(qb8, kb8, ei, nrm, out);
}

// Round 22
// 196.007 us; speedup vs baseline: 1.1440x; 1.0412x over previous
//
#include <hip/hip_runtime.h>
#include <hip/hip_bf16.h>

#define NN   30000
#define DIN  128
#define NHD  256      // H*D
#define HH   4
#define DD   64
#define MM   64
#define KK   6
#define EE   480000
#define ZOFF 1920000  // 30000*64
#define NCS   125
#define CHUNK 240
#define PITCH  30208   // padded bf16 elems per row of kbhT/vbhT
#define PITCH4 3776    // uint4 per row

typedef __attribute__((ext_vector_type(8))) short bf16x8;
typedef __attribute__((ext_vector_type(4))) float f32x4;
typedef __attribute__((ext_vector_type(2))) float f32x2;

__device__ __forceinline__ unsigned f2key(float f) {
    unsigned u = __float_as_uint(f);
    return (u & 0x80000000u) ? ~u : (u | 0x80000000u);
}
__device__ __forceinline__ float key2f(unsigned k) {
    return __uint_as_float((k & 0x80000000u) ? (k ^ 0x80000000u) : ~k);
}
__device__ __forceinline__ unsigned short f2bf(float f) {   // RNE
    unsigned u = __float_as_uint(f);
    unsigned r = ((u >> 16) & 1u) + 0x7fffu;
    return (unsigned short)((u + r) >> 16);
}
__device__ __forceinline__ float bf2f(unsigned short u) {
    return __uint_as_float((unsigned)u << 16);
}
// fp8 e4m3fn, POSITIVE values only, RNE, satfinite (software fallback)
__device__ __forceinline__ unsigned char ftofp8(float x) {
    unsigned u = __float_as_uint(x);
    int e32 = (int)(u >> 23) - 127;
    if (e32 <= -7) {
        int m = (int)rintf(x * 512.f);
        return (unsigned char)m;
    }
    unsigned r = ((u >> 20) & 1u) + 0x7FFFFu;
    u += r;
    e32 = (int)(u >> 23) - 127;
    if (e32 > 8) return 0x7E;
    int m = (u >> 20) & 7;
    return (unsigned char)(((e32 + 7) << 3) | m);
}
__device__ __forceinline__ float fp8tof(unsigned char u) {
    int e = (u >> 3) & 15, m = u & 7;
    if (e == 0) return (float)m * 0.001953125f;
    return __uint_as_float((unsigned)((e + 120) << 23) | ((unsigned)m << 20));
}
// pack 4 f32 -> 4 fp8 bytes (HW converter when available)
__device__ __forceinline__ unsigned fp8pack4(float a, float b, float c, float d) {
#if __has_builtin(__builtin_amdgcn_cvt_pk_fp8_f32)
    int w = __builtin_amdgcn_cvt_pk_fp8_f32(a, b, 0, false);
    w = __builtin_amdgcn_cvt_pk_fp8_f32(c, d, w, true);
    return (unsigned)w;
#else
    return (unsigned)ftofp8(a) | ((unsigned)ftofp8(b) << 8) |
           ((unsigned)ftofp8(c) << 16) | ((unsigned)ftofp8(d) << 24);
#endif
}
// decode 4 fp8 bytes of a uint -> 4 floats (HW converter when available)
__device__ __forceinline__ void fp8x4tof(unsigned w, float* o) {
#if __has_builtin(__builtin_amdgcn_cvt_pk_f32_fp8)
    f32x2 lo = __builtin_amdgcn_cvt_pk_f32_fp8((int)w, false);
    f32x2 hi = __builtin_amdgcn_cvt_pk_f32_fp8((int)w, true);
    o[0] = lo[0]; o[1] = lo[1]; o[2] = hi[0]; o[3] = hi[1];
#else
    o[0] = fp8tof((unsigned char)(w & 255));
    o[1] = fp8tof((unsigned char)((w >> 8) & 255));
    o[2] = fp8tof((unsigned char)((w >> 16) & 255));
    o[3] = fp8tof((unsigned char)((w >> 24) & 255));
#endif
}
__device__ __forceinline__ unsigned short f2h(float x) {   // f32 -> f16 RNE
    _Float16 h = (_Float16)x;
    return *(unsigned short*)&h;
}
__device__ __forceinline__ float h2f(unsigned short u) {
    _Float16 h = *(_Float16*)&u;
    return (float)h;
}

// ---------------------------------------------------------------- init
__global__ void init_kernel(unsigned* gmax) {
    if (threadIdx.x < HH) gmax[threadIdx.x] = 0u;
}

// ---------------------------------------------------------------- K0a: z -> bf16
__global__ __launch_bounds__(256) void zcast_kernel(
    const float* __restrict__ z, unsigned short* __restrict__ zh) {
    int idx = blockIdx.x * 256 + threadIdx.x;   // 960,000 float4 exactly
    float4 v = ((const float4*)z)[idx];
    ushort4 u;
    u.x = f2bf(v.x); u.y = f2bf(v.y); u.z = f2bf(v.z); u.w = f2bf(v.w);
    ((ushort4*)zh)[idx] = u;
}

// ---------------------------------------------------------------- K0b: W [128][256] -> WT bf16 [256][128]
__global__ __launch_bounds__(256) void wtransp_kernel(
    const float* __restrict__ Wq, const float* __restrict__ Wk,
    const float* __restrict__ Wv, unsigned short* __restrict__ WT) {
    __shared__ unsigned short tl[64][72];
    const int t = threadIdx.x;
    const int kt = blockIdx.x & 1, ct = blockIdx.x >> 1;
    const int wi = blockIdx.y;
    const float* W = (wi == 0) ? Wq : (wi == 1) ? Wk : Wv;
    const float4* W4 = (const float4*)W;
    #pragma unroll
    for (int it = 0; it < 4; ++it) {
        int idx = t + it * 256;
        int r = idx >> 4, c4 = idx & 15;
        float4 v = W4[(kt * 64 + r) * 64 + ct * 16 + c4];
        tl[c4 * 4 + 0][r] = f2bf(v.x);
        tl[c4 * 4 + 1][r] = f2bf(v.y);
        tl[c4 * 4 + 2][r] = f2bf(v.z);
        tl[c4 * 4 + 3][r] = f2bf(v.w);
    }
    __syncthreads();
    uint4* d4 = (uint4*)WT;
    #pragma unroll
    for (int it = 0; it < 2; ++it) {
        int idx = t + it * 256;
        int m = idx >> 3, g = idx & 7;
        d4[((size_t)wi * 256 + ct * 64 + m) * 16 + kt * 8 + g] = *(uint4*)&tl[m][g * 8];
    }
}

// ---------------------------------------------------------------- K0c: proj*dn -> bf16
__global__ void projcast_kernel(const float* __restrict__ proj,
                                unsigned short* __restrict__ projh) {
    int i = blockIdx.x * 256 + threadIdx.x;   // 4096 exactly
    projh[i] = f2bf(proj[i] * 0.35355339059327373f);
}

// ---------------------------------------------------------------- K1: qkv via MFMA bf16 (v written transposed)
__global__ __launch_bounds__(256) void qkv_mfma_kernel(
    const unsigned short* __restrict__ zh, const unsigned short* __restrict__ WT,
    const float* __restrict__ bq, const float* __restrict__ bk, const float* __restrict__ bv,
    unsigned short* __restrict__ qh, unsigned short* __restrict__ kh,
    unsigned short* __restrict__ vbhT) {
    __shared__ __align__(16) unsigned short zt[128 * 128];
    __shared__ __align__(16) unsigned short wt[64 * 128];
    const int t = threadIdx.x;
    const int n0 = blockIdx.x * 128;
    const int wi = blockIdx.y;
    const float sc = (wi == 2) ? 1.0f : 2.0f;
    const float* bias = (wi == 0) ? bq : (wi == 1) ? bk : bv;
    unsigned short* outp = (wi == 0) ? qh : kh;
    const uint4* zg = (const uint4*)zh;
    #pragma unroll
    for (int it = 0; it < 8; ++it) {
        int idx = t + it * 256;
        int row = idx >> 4, g = idx & 15;
        int n = n0 + row;
        uint4 v = make_uint4(0u, 0u, 0u, 0u);
        if (n < NN) v = zg[(size_t)n * 16 + g];
        *(uint4*)&zt[row * 128 + ((g ^ (row & 7)) * 8)] = v;
    }
    const uint4* wg = (const uint4*)WT + (size_t)wi * 4096;
    const int w = t >> 6, lane = t & 63, lrow = lane & 15, lk = lane >> 4;
    for (int cc = 0; cc < 4; ++cc) {
        __syncthreads();
        #pragma unroll
        for (int it = 0; it < 4; ++it) {
            int idx = t + it * 256;
            int r = idx >> 4, g = idx & 15;
            *(uint4*)&wt[r * 128 + ((g ^ (r & 7)) * 8)] = wg[(cc * 64 + r) * 16 + g];
        }
        __syncthreads();
        f32x4 acc[4][2];
        #pragma unroll
        for (int mt = 0; mt < 4; ++mt) {
            acc[mt][0] = (f32x4){0.f, 0.f, 0.f, 0.f};
            acc[mt][1] = (f32x4){0.f, 0.f, 0.f, 0.f};
        }
        #pragma unroll
        for (int ks = 0; ks < 4; ++ks) {
            const int g0 = ks * 4 + lk;
            bf16x8 a[4], b[2];
            #pragma unroll
            for (int mt = 0; mt < 4; ++mt) {
                int r = mt * 16 + lrow;
                a[mt] = *(const bf16x8*)&wt[r * 128 + ((g0 ^ (r & 7)) * 8)];
            }
            #pragma unroll
            for (int nt = 0; nt < 2; ++nt) {
                int node = (w * 2 + nt) * 16 + lrow;
                b[nt] = *(const bf16x8*)&zt[node * 128 + ((g0 ^ (node & 7)) * 8)];
            }
            #pragma unroll
            for (int mt = 0; mt < 4; ++mt)
                #pragma unroll
                for (int nt = 0; nt < 2; ++nt)
                    acc[mt][nt] = __builtin_amdgcn_mfma_f32_16x16x32_bf16(
                        a[mt], b[nt], acc[mt][nt], 0, 0, 0);
        }
        if (wi != 2) {
            #pragma unroll
            for (int mt = 0; mt < 4; ++mt) {
                int cbase = cc * 64 + mt * 16 + lk * 4;
                float4 bi = *(const float4*)&bias[cbase];
                #pragma unroll
                for (int nt = 0; nt < 2; ++nt) {
                    int n = n0 + (w * 2 + nt) * 16 + lrow;
                    if (n < NN) {
                        ushort4 u;
                        u.x = f2bf((acc[mt][nt][0] + bi.x) * sc);
                        u.y = f2bf((acc[mt][nt][1] + bi.y) * sc);
                        u.z = f2bf((acc[mt][nt][2] + bi.z) * sc);
                        u.w = f2bf((acc[mt][nt][3] + bi.w) * sc);
                        *(ushort4*)&outp[(size_t)n * NHD + cbase] = u;
                    }
                }
            }
        } else {
            // v path: stage transposed tile into wt (dead after MFMA), then write vbhT.
            // cc == head h here (64-col chunks align with heads).
            __syncthreads();   // all waves done reading wt
            #pragma unroll
            for (int mt = 0; mt < 4; ++mt) {
                int cbase = cc * 64 + mt * 16 + lk * 4;
                int lc = mt * 16 + lk * 4;
                float4 bi = *(const float4*)&bias[cbase];
                #pragma unroll
                for (int nt = 0; nt < 2; ++nt) {
                    int nloc = (w * 2 + nt) * 16 + lrow;
                    int n = n0 + nloc;
                    ushort4 u = make_ushort4(0, 0, 0, 0);
                    if (n < NN) {
                        u.x = f2bf(acc[mt][nt][0] + bi.x);
                        u.y = f2bf(acc[mt][nt][1] + bi.y);
                        u.z = f2bf(acc[mt][nt][2] + bi.z);
                        u.w = f2bf(acc[mt][nt][3] + bi.w);
                    }
                    wt[(lc + 0) * 128 + nloc] = u.x;
                    wt[(lc + 1) * 128 + nloc] = u.y;
                    wt[(lc + 2) * 128 + nloc] = u.z;
                    wt[(lc + 3) * 128 + nloc] = u.w;
                }
            }
            __syncthreads();
            uint4* d4v = (uint4*)vbhT;
            #pragma unroll
            for (int it = 0; it < 4; ++it) {
                int idx = t + it * 256;       // 1024 = 64 rows x 16 uint4
                int row = idx >> 4, g = idx & 15;
                d4v[(size_t)(cc * 64 + row) * PITCH4 + (n0 >> 3) + g] =
                    *(uint4*)&wt[row * 128 + g * 8];
            }
        }
    }
}

// ---------------------------------------------------------------- K2: random features via MFMA (+ fused fp8 qp, f16 kb)
__global__ __launch_bounds__(256) void feat_mfma_kernel(
    unsigned short* __restrict__ qbh, const unsigned short* __restrict__ kh,
    unsigned short* __restrict__ kbf, const unsigned short* __restrict__ projh,
    unsigned* __restrict__ gmax, unsigned char* __restrict__ qb8) {
    __shared__ __align__(16) unsigned short at[64 * 64];
    __shared__ __align__(16) unsigned short pb[64 * 64];
    __shared__ __align__(16) float ddt[64 * 68];
    __shared__ float diag_sh[64];
    __shared__ float wmax_sh[4];
    const int t = threadIdx.x;
    const int h = blockIdx.y;
    const int n0 = blockIdx.x * 64;
    const int tx = t & 15, ty = t >> 4;
    const uint4* pg = (const uint4*)projh;
    #pragma unroll
    for (int q = 0; q < 2; ++q) {
        int idx = t + q * 256;
        int m = idx >> 3, g = idx & 7;
        *(uint4*)&pb[m * 64 + ((g ^ (m & 7)) * 8)] = pg[idx];
    }
    const int w = t >> 6, lane = t & 63, lrow = lane & 15, lk = lane >> 4;
    const int arow = w * 16 + lrow;
    #pragma unroll
    for (int pass = 0; pass < 2; ++pass) {
        const uint4* src = (const uint4*)(pass ? kh : qbh);
        __syncthreads();
        #pragma unroll
        for (int q = 0; q < 2; ++q) {
            int idx = t + q * 256;
            int n = idx >> 3, g = idx & 7;
            uint4 v = make_uint4(0u, 0u, 0u, 0u);
            if (n0 + n < NN) v = src[(size_t)(n0 + n) * 32 + h * 8 + g];
            *(uint4*)&at[n * 64 + ((g ^ (n & 7)) * 8)] = v;
            const unsigned short* e8 = (const unsigned short*)&v;
            float ss = 0.f;
            #pragma unroll
            for (int j2 = 0; j2 < 8; ++j2) { float f = bf2f(e8[j2]); ss += f * f; }
            ss += __shfl_xor(ss, 1, 64);
            ss += __shfl_xor(ss, 2, 64);
            ss += __shfl_xor(ss, 4, 64);
            if (g == 0) diag_sh[n] = 0.0625f * ss;   // 0.5 * dn^2 * sum
        }
        __syncthreads();
        bf16x8 a0 = *(const bf16x8*)&at[arow * 64 + ((lk ^ (arow & 7)) * 8)];
        bf16x8 a1 = *(const bf16x8*)&at[arow * 64 + (((lk + 4) ^ (arow & 7)) * 8)];
        #pragma unroll
        for (int ct = 0; ct < 4; ++ct) {
            int brow = ct * 16 + lrow;
            bf16x8 b0 = *(const bf16x8*)&pb[brow * 64 + ((lk ^ (brow & 7)) * 8)];
            bf16x8 b1 = *(const bf16x8*)&pb[brow * 64 + (((lk + 4) ^ (brow & 7)) * 8)];
            f32x4 acc = {0.f, 0.f, 0.f, 0.f};
            acc = __builtin_amdgcn_mfma_f32_16x16x32_bf16(a0, b0, acc, 0, 0, 0);
            acc = __builtin_amdgcn_mfma_f32_16x16x32_bf16(a1, b1, acc, 0, 0, 0);
            #pragma unroll
            for (int r = 0; r < 4; ++r)
                ddt[(w * 16 + lk * 4 + r) * 68 + ct * 16 + lrow] = acc[r];
        }
        __syncthreads();
        if (pass == 0) {
            #pragma unroll
            for (int i = 0; i < 4; ++i) {
                int n = n0 + ty * 4 + i;
                float a_[4];
                #pragma unroll
                for (int j = 0; j < 4; ++j) a_[j] = ddt[(ty * 4 + i) * 68 + tx * 4 + j];
                float mx = fmaxf(fmaxf(a_[0], a_[1]), fmaxf(a_[2], a_[3]));
                mx = fmaxf(mx, __shfl_xor(mx, 1, 64));
                mx = fmaxf(mx, __shfl_xor(mx, 2, 64));
                mx = fmaxf(mx, __shfl_xor(mx, 4, 64));
                mx = fmaxf(mx, __shfl_xor(mx, 8, 64));
                if (n < NN) {
                    float dg = diag_sh[ty * 4 + i] + mx;
                    float f0 = 0.125f * (__expf(a_[0] - dg) + 1e-6f);
                    float f1 = 0.125f * (__expf(a_[1] - dg) + 1e-6f);
                    float f2 = 0.125f * (__expf(a_[2] - dg) + 1e-6f);
                    float f3 = 0.125f * (__expf(a_[3] - dg) + 1e-6f);
                    ushort4 u;
                    u.x = f2bf(f0); u.y = f2bf(f1); u.z = f2bf(f2); u.w = f2bf(f3);
                    *(ushort4*)&qbh[(size_t)n * NHD + h * DD + tx * 4] = u;
                    unsigned pk = fp8pack4(bf2f(u.x) * 2048.f, bf2f(u.y) * 2048.f,
                                           bf2f(u.z) * 2048.f, bf2f(u.w) * 2048.f);
                    *(unsigned*)&qb8[(size_t)n * NHD + h * DD + tx * 4] = pk;
                }
            }
        } else {
            float km = -3.4e38f;
            #pragma unroll
            for (int i = 0; i < 4; ++i) {
                int n = n0 + ty * 4 + i;
                if (n < NN) {
                    float a_[4];
                    #pragma unroll
                    for (int j = 0; j < 4; ++j) a_[j] = ddt[(ty * 4 + i) * 68 + tx * 4 + j];
                    float dg = diag_sh[ty * 4 + i];
                    ushort4 o;
                    o.x = f2h(a_[0] - dg); o.y = f2h(a_[1] - dg);
                    o.z = f2h(a_[2] - dg); o.w = f2h(a_[3] - dg);
                    *(ushort4*)&kbf[(size_t)n * NHD + h * DD + tx * 4] = o;
                    km = fmaxf(km, fmaxf(fmaxf(a_[0], a_[1]), fmaxf(a_[2], a_[3])));
                }
            }
            #pragma unroll
            for (int off = 1; off < 64; off <<= 1) km = fmaxf(km, __shfl_xor(km, off, 64));
            if ((t & 63) == 0) wmax_sh[t >> 6] = km;
            __syncthreads();
            if (t == 0) {
                float m2 = fmaxf(fmaxf(wmax_sh[0], wmax_sh[1]), fmaxf(wmax_sh[2], wmax_sh[3]));
                atomicMax(&gmax[h], f2key(m2));
            }
        }
    }
}

// ---------------------------------------------------------------- K3: fused kp finalize + transpose + fp8 (f16 in)
__global__ __launch_bounds__(256) void kfin_tr_kernel(
    const unsigned short* __restrict__ kbf, const unsigned* __restrict__ gmax,
    unsigned short* __restrict__ kbh, unsigned short* __restrict__ kbhT,
    unsigned char* __restrict__ kb8) {
    __shared__ unsigned short tl[64][72];
    const int t = threadIdx.x;
    const int n0 = blockIdx.x * 64;
    const int h = blockIdx.y;
    const float mx = key2f(gmax[h]);
    const ushort4* s4 = (const ushort4*)kbf;
    #pragma unroll
    for (int it = 0; it < 4; ++it) {
        int idx = t + it * 256;
        int n = idx >> 4, c4 = idx & 15;
        ushort4 u = make_ushort4(0, 0, 0, 0);
        if (n0 + n < NN) {
            ushort4 v = s4[(size_t)(n0 + n) * 64 + h * 16 + c4];
            float f0 = 0.125f * (__expf(h2f(v.x) - mx) + 1e-6f);
            float f1 = 0.125f * (__expf(h2f(v.y) - mx) + 1e-6f);
            float f2 = 0.125f * (__expf(h2f(v.z) - mx) + 1e-6f);
            float f3 = 0.125f * (__expf(h2f(v.w) - mx) + 1e-6f);
            u.x = f2bf(f0); u.y = f2bf(f1); u.z = f2bf(f2); u.w = f2bf(f3);
            *(ushort4*)&kbh[(size_t)(n0 + n) * NHD + h * DD + c4 * 4] = u;
            unsigned pk = fp8pack4(bf2f(u.x) * 2048.f, bf2f(u.y) * 2048.f,
                                   bf2f(u.z) * 2048.f, bf2f(u.w) * 2048.f);
            *(unsigned*)&kb8[(size_t)(n0 + n) * NHD + h * DD + c4 * 4] = pk;
        }
        tl[c4 * 4 + 0][n] = u.x;
        tl[c4 * 4 + 1][n] = u.y;
        tl[c4 * 4 + 2][n] = u.z;
        tl[c4 * 4 + 3][n] = u.w;
    }
    __syncthreads();
    uint4* d4 = (uint4*)kbhT;
    #pragma unroll
    for (int it = 0; it < 2; ++it) {
        int idx = t + it * 256;
        int m = idx >> 3, g = idx & 7;
        d4[(size_t)(h * 64 + m) * PITCH4 + (n0 >> 3) + g] = *(uint4*)&tl[m][g * 8];
    }
}

// ---------------------------------------------------------------- K4: kvs via MFMA bf16 (hoisted kpw, NCS grid)
__global__ __launch_bounds__(512) void kvs_kernel(
    const unsigned short* __restrict__ kbhT, const unsigned short* __restrict__ vbhT,
    const float* __restrict__ gum,
    unsigned short* __restrict__ kvsp, float* __restrict__ ksp, float* __restrict__ ksump) {
    __shared__ __align__(16) unsigned short va [64 * 64];
    __shared__ __align__(16) unsigned short kpw[KK][64 * 64];
    __shared__ float w_sh[KK][256];
    const int c = blockIdx.x, h = blockIdx.y;
    const int t = threadIdx.x;
    const int n0 = c * CHUNK;
    const int n1 = n0 + CHUNK;
    for (int i = t; i < 256; i += 512) {
        int n = n0 + i;
        bool ok = (i < CHUNK);
        #pragma unroll
        for (int k = 0; k < KK; ++k)
            w_sh[k][i] = ok ? __expf(gum[n * 24 + h * KK + k] * 4.0f) : 0.f;
    }
    const int m_ = t >> 3, g_ = t & 7;
    const int w = t >> 6, lane = t & 63, lrow = lane & 15, lk = lane >> 4;
    const int ds = w & 3, mh = w >> 2;
    const int arow = ds * 16 + lrow;
    f32x4 acc[KK][2];
    #pragma unroll
    for (int k = 0; k < KK; ++k) {
        acc[k][0] = (f32x4){0.f, 0.f, 0.f, 0.f};
        acc[k][1] = (f32x4){0.f, 0.f, 0.f, 0.f};
    }
    float ks_acc[KK] = {0.f, 0.f, 0.f, 0.f, 0.f, 0.f};
    float ksum_acc = 0.f;
    const uint4* kT4 = (const uint4*)kbhT;
    const uint4* vT4 = (const uint4*)vbhT;
    __syncthreads();   // w_sh ready
    #pragma unroll
    for (int s = 0; s < 4; ++s) {
        const int nb = n0 + s * 64;
        uint4 kvv = kT4[(size_t)(h * 64 + m_) * PITCH4 + (nb >> 3) + g_];
        uint4 vvv = vT4[(size_t)(h * 64 + m_) * PITCH4 + (nb >> 3) + g_];
        const int slot = g_ ^ (m_ & 7);
        *(uint4*)&va[m_ * 64 + slot * 8] = vvv;
        float kf[8];
        {
            const unsigned short* ke = (const unsigned short*)&kvv;
            float sl = 0.f;
            int nbase = nb + g_ * 8;
            #pragma unroll
            for (int e = 0; e < 8; ++e) {
                kf[e] = bf2f(ke[e]);
                if (nbase + e < n1) sl += kf[e];
            }
            sl += __shfl_xor(sl, 1, 64);
            sl += __shfl_xor(sl, 2, 64);
            sl += __shfl_xor(sl, 4, 64);
            if (g_ == 0) ksum_acc += sl;
        }
        const int bw = s * 64;
        const int gg = g_ ^ (m_ & 7);
        #pragma unroll
        for (int k = 0; k < KK; ++k) {
            unsigned short ov[8];
            float sl = 0.f;
            #pragma unroll
            for (int e = 0; e < 8; ++e) {
                float p = kf[e] * w_sh[k][bw + gg * 8 + e];
                sl += p;
                ov[e] = f2bf(p);
            }
            *(uint4*)&kpw[k][m_ * 64 + g_ * 8] = *(uint4*)ov;
            sl += __shfl_xor(sl, 1, 64);
            sl += __shfl_xor(sl, 2, 64);
            sl += __shfl_xor(sl, 4, 64);
            if (g_ == 0) ks_acc[k] += sl;
        }
        __syncthreads();
        bf16x8 a0 = *(const bf16x8*)&va[arow * 64 + ((lk ^ (arow & 7)) * 8)];
        bf16x8 a1 = *(const bf16x8*)&va[arow * 64 + (((lk + 4) ^ (arow & 7)) * 8)];
        #pragma unroll
        for (int k = 0; k < KK; ++k) {
            #pragma unroll
            for (int mt = 0; mt < 2; ++mt) {
                int m = (mh * 2 + mt) * 16 + lrow;
                bf16x8 b0 = *(const bf16x8*)&kpw[k][m * 64 + ((lk ^ (m & 7)) * 8)];
                bf16x8 b1 = *(const bf16x8*)&kpw[k][m * 64 + (((lk + 4) ^ (m & 7)) * 8)];
                acc[k][mt] = __builtin_amdgcn_mfma_f32_16x16x32_bf16(a0, b0, acc[k][mt], 0, 0, 0);
                acc[k][mt] = __builtin_amdgcn_mfma_f32_16x16x32_bf16(a1, b1, acc[k][mt], 0, 0, 0);
            }
        }
        __syncthreads();
    }
    const size_t cb = (size_t)(c * HH + h) * KK;
    #pragma unroll
    for (int k = 0; k < KK; ++k)
        #pragma unroll
        for (int mt = 0; mt < 2; ++mt) {
            int m = (mh * 2 + mt) * 16 + lrow;
            #pragma unroll
            for (int r = 0; r < 4; ++r) {
                int d = ds * 16 + lk * 4 + r;
                kvsp[(cb + k) * 4096 + d * 64 + m] = f2bf(acc[k][mt][r]);
            }
        }
    if (g_ == 0) {
        #pragma unroll
        for (int k = 0; k < KK; ++k)
            ksp[(cb + k) * 64 + m_] = ks_acc[k];
        ksump[(size_t)(c * HH + h) * 64 + m_] = ksum_acc;
    }
}

// ---------------------------------------------------------------- K5: reduce bf16 partials
__global__ void reduce_kernel(const unsigned short* __restrict__ kvsp,
                              const float* __restrict__ ksp, const float* __restrict__ ksump,
                              unsigned short* __restrict__ kvshT, float* __restrict__ kss,
                              float* __restrict__ ksum) {
    int idx = blockIdx.x * 256 + threadIdx.x;
    if (idx < 98304) {
        float s = 0.f;
        for (int c = 0; c < NCS; ++c) s += bf2f(kvsp[c * 98304 + idx]);
        kvshT[idx] = f2bf(s);
    } else if (idx < 98304 + 1536) {
        int o = idx - 98304;
        float s = 0.f;
        for (int c = 0; c < NCS; ++c) s += ksp[c * 1536 + o];
        kss[o] = s;
    } else if (idx < 98304 + 1536 + 256) {
        int o = idx - 98304 - 1536;
        float s = 0.f;
        for (int c = 0; c < NCS; ++c) s += ksump[c * 256 + o];
        ksum[o] = s;
    }
}

// ---------------------------------------------------------------- K6: znum via MFMA bf16 (512 thr, MFMA z_den)
__global__ __launch_bounds__(512) void znum_kernel(
    const unsigned short* __restrict__ qbh, const unsigned short* __restrict__ kvshT,
    const float* __restrict__ kss, const float* __restrict__ ksum,
    unsigned short* __restrict__ zouth, float* __restrict__ nrm) {
    __shared__ __align__(16) unsigned short qpa[64 * 64];
    __shared__ __align__(16) unsigned short bt[6 * 64 * 64];
    __shared__ __align__(16) unsigned short bbuf[16 * 72];
    __shared__ float zdi[64 * 6];
    const int t = threadIdx.x;
    const int h = blockIdx.y;
    const int n0 = blockIdx.x * 64;
    const uint4* qg = (const uint4*)qbh;
    {
        int row = t >> 3, c8 = t & 7;
        int n = n0 + row;
        uint4 v = make_uint4(0u, 0u, 0u, 0u);
        if (n < NN) v = qg[n * 32 + h * 8 + c8];
        *(uint4*)&qpa[row * 64 + ((c8 ^ (row & 7)) * 8)] = v;
    }
    const uint4* bg = (const uint4*)kvshT;
    #pragma unroll
    for (int q = 0; q < 6; ++q) {
        int idx = t + q * 512;
        int kd = idx >> 3, c8 = idx & 7;
        *(uint4*)&bt[kd * 64 + ((c8 ^ (kd & 7)) * 8)] = bg[h * 3072 + idx];
    }
    #pragma unroll
    for (int q = 0; q < 2; ++q) {
        int idx = t + q * 512;
        int col = idx >> 6, m = idx & 63;
        float v = 0.f;
        if (col < 6) v = kss[h * 384 + col * 64 + m];
        else if (col == 6) v = ksum[h * 64 + m];
        bbuf[col * 72 + m] = f2bf(v);
    }
    __syncthreads();
    const int w = t >> 6, lane = t & 63;
    const int lrow = lane & 15, lk = lane >> 4;
    const int w2 = w & 3, wh = w >> 2;
    const int arow = w2 * 16 + lrow;
    const int aswz = (arow & 7) << 3;
    bf16x8 a0 = *(const bf16x8*)&qpa[arow * 64 + ((lk * 8) ^ aswz)];
    bf16x8 a1 = *(const bf16x8*)&qpa[arow * 64 + ((lk * 8 + 32) ^ aswz)];
    if (wh == 0) {
        bf16x8 b0 = *(const bf16x8*)&bbuf[lrow * 72 + lk * 8];
        bf16x8 b1 = *(const bf16x8*)&bbuf[lrow * 72 + lk * 8 + 32];
        f32x4 acc = {0.f, 0.f, 0.f, 0.f};
        acc = __builtin_amdgcn_mfma_f32_16x16x32_bf16(a0, b0, acc, 0, 0, 0);
        acc = __builtin_amdgcn_mfma_f32_16x16x32_bf16(a1, b1, acc, 0, 0, 0);
        #pragma unroll
        for (int r = 0; r < 4; ++r) {
            int node = w2 * 16 + lk * 4 + r;
            if (lrow < 6) zdi[node * 6 + lrow] = 1.0f / acc[r];
            else if (lrow == 6) {
                int n = n0 + node;
                if (n < NN) nrm[n * HH + h] = acc[r];
            }
        }
    }
    __syncthreads();
    const float inv6 = 1.0f / 6.0f;
    #pragma unroll
    for (int dtt = 0; dtt < 2; ++dtt) {
        const int dt = wh * 2 + dtt;
        f32x4 outv = {0.f, 0.f, 0.f, 0.f};
        #pragma unroll
        for (int k = 0; k < KK; ++k) {
            int kd = k * 64 + dt * 16 + lrow;
            int sw = (kd & 7) << 3;
            bf16x8 b0 = *(const bf16x8*)&bt[kd * 64 + ((lk * 8) ^ sw)];
            bf16x8 b1 = *(const bf16x8*)&bt[kd * 64 + ((lk * 8 + 32) ^ sw)];
            f32x4 acc = {0.f, 0.f, 0.f, 0.f};
            acc = __builtin_amdgcn_mfma_f32_16x16x32_bf16(a0, b0, acc, 0, 0, 0);
            acc = __builtin_amdgcn_mfma_f32_16x16x32_bf16(a1, b1, acc, 0, 0, 0);
            #pragma unroll
            for (int r = 0; r < 4; ++r)
                outv[r] += zdi[(w2 * 16 + lk * 4 + r) * 6 + k] * acc[r];
        }
        #pragma unroll
        for (int r = 0; r < 4; ++r) {
            int n = n0 + w2 * 16 + lk * 4 + r;
            if (n < NN) zouth[(size_t)n * NHD + h * DD + dt * 16 + lrow] = f2bf(outv[r] * inv6);
        }
    }
}

// ---------------------------------------------------------------- K7: output projection (bf16 in, f32 out)
__global__ __launch_bounds__(256) void outproj_kernel(
    const unsigned short* __restrict__ zouth, const float* __restrict__ Wo,
    const float* __restrict__ bo, float* __restrict__ out) {
    __shared__ float zsh[16][NHD];
    const int t = threadIdx.x;
    const int n0 = blockIdx.x * 16;
    const uint4* zg = (const uint4*)zouth;
    #pragma unroll
    for (int q = 0; q < 2; ++q) {
        int idx = t + q * 256;
        int row = idx >> 5, g = idx & 31;
        uint4 v = zg[(size_t)(n0 + row) * 32 + g];
        const unsigned short* e = (const unsigned short*)&v;
        #pragma unroll
        for (int j = 0; j < 8; ++j) zsh[row][g * 8 + j] = bf2f(e[j]);
    }
    __syncthreads();
    const int c = t & 63, g = t >> 6;
    float acc[4];
    #pragma unroll
    for (int i = 0; i < 4; ++i) acc[i] = bo[c];
    for (int r = 0; r < 256; ++r) {
        float w = Wo[r * 64 + c];
        #pragma unroll
        for (int i = 0; i < 4; ++i) acc[i] += zsh[g + 4 * i][r] * w;
    }
    #pragma unroll
    for (int i = 0; i < 4; ++i)
        out[(n0 + g + 4 * i) * 64 + c] = acc[i];
}

// ---------------------------------------------------------------- K8: edges, fp8 gather + HW decode
__global__ __launch_bounds__(256) void edge_fp8_kernel(
    const unsigned char* __restrict__ qb8, const unsigned char* __restrict__ kb8,
    const int* __restrict__ ei, const float* __restrict__ nrm,
    float* __restrict__ out) {
    const int t = threadIdx.x;
    const int li = t & 15;
    const int e = blockIdx.x * 16 + (t >> 4);
    const int s = ei[e], d = ei[EE + e];
    uint4 qv = ((const uint4*)qb8)[d * 16 + li];
    uint4 kv = ((const uint4*)kb8)[s * 16 + li];
    float qf[16], kf[16];
    fp8x4tof(qv.x, qf + 0);  fp8x4tof(qv.y, qf + 4);
    fp8x4tof(qv.z, qf + 8);  fp8x4tof(qv.w, qf + 12);
    fp8x4tof(kv.x, kf + 0);  fp8x4tof(kv.y, kf + 4);
    fp8x4tof(kv.z, kf + 8);  fp8x4tof(kv.w, kf + 12);
    float p = 0.f;
    #pragma unroll
    for (int i = 0; i < 16; ++i) p = fmaf(qf[i], kf[i], p);
    p += __shfl_xor(p, 1, 64);
    p += __shfl_xor(p, 2, 64);
    if ((li & 3) == 0) {
        int h = li >> 2;
        out[ZOFF + e * 4 + h] = p * (1.0f / (2048.f * 2048.f)) / nrm[d * HH + h];
    }
}

// ---------------------------------------------------------------- launch
extern "C" void kernel_launch(void* const* d_in, const int* in_sizes, int n_in,
                              void* d_out, int out_size, void* d_ws, size_t ws_size,
                              hipStream_t stream) {
    (void)in_sizes; (void)n_in; (void)out_size;
    const float* z  = (const float*)d_in[0];
    const float* Wq = (const float*)d_in[1];
    const float* bq = (const float*)d_in[2];
    const float* Wk = (const float*)d_in[3];
    const float* bk = (const float*)d_in[4];
    const float* Wv = (const float*)d_in[5];
    const float* bv = (const float*)d_in[6];
    const float* Wo = (const float*)d_in[7];
    const float* bo = (const float*)d_in[8];
    const float* proj = (const float*)d_in[9];
    const float* gum  = (const float*)d_in[10];
    const int*   ei   = (const int*)d_in[11];
    float* out = (float*)d_out;
    float* ws = (float*)d_ws;

    if (ws_size / 4 < (size_t)38673348) return;

    // region map (floats):
    // [0, 1.92M)       : zh (pre-qkv) -> qb8 (feat onward, read by edge)
    // [1.92M, 3.84M)   : zh tail -> kb8 (kfin_tr onward, read by edge)
    // [3.84M, 4.0M)    : WT (pre-qkv only)
    // [4.0M, 10.15M)   : kvsp bf16 (kvs->reduce; kbf region dead after kfin_tr)
    // [7.68M, 11.52M)  : kbf f16 (feat -> kfin_tr, then dead)  [inside kvsp span, sequenced]
    // [15.36M, 17.28M) : zouth bf16 (znum->outproj)
    // [16.3M, 16.77M)  : ksp + ksump (kvs->reduce; dead before znum writes zouth)
    // [23.04M ...)     : kvshT, projh, kss, ksum, nrm, gmax, qbh, kbh, kbhT, vbhT
    unsigned short* kbf = (unsigned short*)(ws + 7680000);     // 7.68M f16 elems
    unsigned short* zouth = (unsigned short*)(ws + 15360000);
    unsigned short* kvshT = (unsigned short*)(ws + 23040000);
    unsigned short* projh = (unsigned short*)(ws + 23089152);
    float* kss   = ws + 23138304;
    float* ksum  = ws + 23139840;
    float* nrm   = ws + 23140096;
    unsigned* gmax = (unsigned*)(ws + 23260096);
    unsigned short* qbh = (unsigned short*)(ws + 23260100);
    unsigned short* kbh = (unsigned short*)(ws + 27100100);
    unsigned short* kbhT = (unsigned short*)(ws + 30940100);
    unsigned short* vbhT = (unsigned short*)(ws + 34806724);
    unsigned short* zh = (unsigned short*)ws;                  // dead after qkv
    unsigned short* WT = (unsigned short*)(ws + 3840000);      // dead after qkv
    unsigned char* qb8 = (unsigned char*)ws;                   // 7.68M bytes
    unsigned char* kb8 = (unsigned char*)(ws + 1920000);       // 7.68M bytes
    unsigned short* kvsp = (unsigned short*)(ws + 4000000);    // NCS*98304 bf16 (kbf dead by kvs)
    float* ksp   = ws + 16300000;                              // NCS*1536
    float* ksump = ws + 16700000;                              // NCS*256

    init_kernel<<<1, 64, 0, stream>>>(gmax);
    zcast_kernel<<<3750, 256, 0, stream>>>(z, zh);
    wtransp_kernel<<<dim3(8, 3), 256, 0, stream>>>(Wq, Wk, Wv, WT);
    projcast_kernel<<<16, 256, 0, stream>>>(proj, projh);
    qkv_mfma_kernel<<<dim3(235, 3), 256, 0, stream>>>(zh, WT, bq, bk, bv, qbh, kbh, vbhT);
    feat_mfma_kernel<<<dim3(469, HH), 256, 0, stream>>>(qbh, kbh, kbf, projh, gmax, qb8);
    kfin_tr_kernel<<<dim3(472, HH), 256, 0, stream>>>(kbf, gmax, kbh, kbhT, kb8);
    kvs_kernel<<<dim3(NCS, HH), 512, 0, stream>>>(kbhT, vbhT, gum, kvsp, ksp, ksump);
    reduce_kernel<<<392, 256, 0, stream>>>(kvsp, ksp, ksump, kvshT, kss, ksum);
    znum_kernel<<<dim3(469, HH), 512, 0, stream>>>(qbh, kvshT, kss, ksum, zouth, nrm);
    outproj_kernel<<<1875, 256, 0, stream>>>(zouth, Wo, bo, out);
    edge_fp8_kernel<<<30000, 256, 0, stream>>>(qb8, kb8, ei, nrm, out);
}